// Round 17
// baseline (556.310 us; speedup 1.0000x reference)
//
#include <hip/hip_runtime.h>
#include <hip/hip_bf16.h>
#include <stdint.h>

// ---------------------------------------------------------------------------
// PytorchLlamaSDPA: GQA attention (64 q-heads, 8 kv-heads, S=KV=2048, D=128)
// + additive mask (s,t) + softmax + PV + output projection (8192x8192^T).
// bf16 MFMA, fp32 softmax/accum.
// Attention: r16 (best measured): 4-warp 256-thread blocks, 2 blocks/CU.
// GEMM: 256x128 tile, 512 blocks -> 2 blocks/CU (TLP fills stalls). BK=32,
//   dbuf LDS 48KB, d-pair-packed 128B rows (<=2-way banks), counted vmcnt(3).
// ---------------------------------------------------------------------------

typedef __bf16 bf16;
typedef __attribute__((ext_vector_type(8))) __bf16 bf16x8;
typedef __attribute__((ext_vector_type(4))) __bf16 bf16x4;
typedef __attribute__((ext_vector_type(4))) float f32x4;
typedef __attribute__((ext_vector_type(16))) float f32x16;
typedef __attribute__((ext_vector_type(4))) unsigned int u32x4;

#define N_HEADS 64
#define N_KVH   8
#define HDIM    128
#define SEQ     2048
#define KVL     2048
#define DIM     8192

__device__ __forceinline__ void gload16(const void* g, void* l) {
  __builtin_amdgcn_global_load_lds((const __attribute__((address_space(1))) void*)g,
                                   (__attribute__((address_space(3))) void*)l,
                                   16, 0, 0);
}

// pack two floats to one u32 of two bf16 (lo in bits 15:0) - pure bit ops
__device__ __forceinline__ unsigned pack2(float lo, float hi) {
  union { bf16 h; unsigned short u; } a, b;
  a.h = (bf16)lo; b.h = (bf16)hi;
  return ((unsigned)b.u << 16) | (unsigned)a.u;
}

// cross-half exchange via v_permlane32_swap_b32 (verified r11)
__device__ __forceinline__ void exch(unsigned a, unsigned b, unsigned& r0, unsigned& r1) {
  asm("v_permlane32_swap_b32 %0, %1" : "+v"(a), "+v"(b));
  r0 = a; r1 = b;
}

// Build two PV B-operand fragments (kv-slices of 16) from one 32-kv P strip.
__device__ __forceinline__ void buildfrags(const float (&p)[16], bf16x8& f0, bf16x8& f1) {
  unsigned pk0 = pack2(p[0],  p[1]),  pk1 = pack2(p[2],  p[3]);
  unsigned pk2 = pack2(p[4],  p[5]),  pk3 = pack2(p[6],  p[7]);
  unsigned pk4 = pack2(p[8],  p[9]),  pk5 = pack2(p[10], p[11]);
  unsigned pk6 = pack2(p[12], p[13]), pk7 = pack2(p[14], p[15]);
  unsigned a0, a1, b0, b1, c0, c1, d0, d1;
  exch(pk0, pk2, a0, a1);
  exch(pk1, pk3, b0, b1);
  exch(pk4, pk6, c0, c1);
  exch(pk5, pk7, d0, d1);
  u32x4 w0 = { a0, b0, a1, b1 };
  u32x4 w1 = { c0, d0, c1, d1 };
  f0 = __builtin_bit_cast(bf16x8, w0);
  f1 = __builtin_bit_cast(bf16x8, w1);
}

// --------------------------- fp32 -> bf16 (flat, scaled) -------------------
__global__ void cvt_f32_bf16(const float* __restrict__ in, bf16* __restrict__ out,
                             int n4, float scale) {
  int i = blockIdx.x * blockDim.x + threadIdx.x;
  int stride = gridDim.x * blockDim.x;
  for (; i < n4; i += stride) {
    float4 v = ((const float4*)in)[i];
    bf16x4 o = { (bf16)(v.x * scale), (bf16)(v.y * scale),
                 (bf16)(v.z * scale), (bf16)(v.w * scale) };
    *(bf16x4*)(out + (long)i * 4) = o;
  }
}

// ------------------- values (kh,t,d) -> bf16 V^T (kh,d,t) ------------------
__global__ void cvt_vT_kernel(const float* __restrict__ v, bf16* __restrict__ vT) {
  __shared__ bf16 tile[64][132];
  const int tid = threadIdx.x;
  const int kh = blockIdx.x >> 5;
  const int t0 = (blockIdx.x & 31) << 6;
  const float* src = v + ((long)kh * KVL + t0) * HDIM;
#pragma unroll
  for (int it = 0; it < 8; ++it) {
    int q = it * 256 + tid;
    int r = q >> 5;
    int c4 = (q & 31) << 2;
    float4 val = *(const float4*)(src + (long)r * HDIM + c4);
    bf16x4 o = { (bf16)val.x, (bf16)val.y, (bf16)val.z, (bf16)val.w };
    *(bf16x4*)&tile[r][c4] = o;
  }
  __syncthreads();
  const int t = tid & 63;
  const int dbase = tid >> 6;
#pragma unroll
  for (int it = 0; it < 32; ++it) {
    int d = it * 4 + dbase;
    vT[((long)kh * HDIM + d) * KVL + t0 + t] = tile[t][d];
  }
}

// ------------------------------- attention ---------------------------------
// r16 (best): Grid 1024 = 64 heads x 16 q-blocks of 128 rows, 256 threads
// (4 warps), 2 blocks/CU. K dbuf 2x16KB [0,32K) + V d-paired dbuf 2x16KB
// [32K,64K). All LDS reads <=2-way banked. Scale pre-folded into Q.
__global__ __launch_bounds__(256, 2) void attn_kernel(
    const bf16* __restrict__ qB, const bf16* __restrict__ kB,
    const bf16* __restrict__ vT, const float* __restrict__ mask,
    bf16* __restrict__ attnB)
{
  __shared__ __align__(16) char lds[65536];

  const int tid  = threadIdx.x;
  const int lane = tid & 63;
  const int w    = tid >> 6;       // 0..3
  const int ihi  = lane >> 5;
  const int l31  = lane & 31;

  const int bid = blockIdx.x;
  const int h   = bid >> 4;
  const int q0b = (bid & 15) << 7;
  const int kh  = h >> 3;

  // ---- stage Q [128 rows][256B], key &15 ----
#pragma unroll
  for (int rnd = 0; rnd < 8; ++rnd) {
    int row = rnd * 16 + w * 4 + (lane >> 4);
    int cg  = (lane & 15) ^ (row & 15);
    const bf16* g = qB + (((long)(q0b + row) * N_HEADS + h) << 7) + (cg << 3);
    gload16(g, lds + rnd * 4096 + w * 1024);
  }
  __syncthreads();

  bf16x8 qf[8];
  {
    int qrow = (w << 5) + l31;      // 0..127
    const char* qr = lds + qrow * 256;
#pragma unroll
    for (int s = 0; s < 8; ++s)
      qf[s] = *(const bf16x8*)(qr + ((((s << 1) | ihi) ^ (qrow & 15)) << 4));
  }
  __syncthreads();   // Q area freed -> K double buffer

  // ---- stage K/V tile 0 into buffer 0 ----
  {
#pragma unroll
    for (int rnd = 0; rnd < 4; ++rnd) {
      int row = rnd * 16 + w * 4 + (lane >> 4);
      int cg  = (lane & 15) ^ (row & 15);
      const bf16* g = kB + (((long)(kh * KVL + row)) << 7) + (cg << 3);
      gload16(g, lds + rnd * 4096 + w * 1024);
    }
#pragma unroll
    for (int rnd = 0; rnd < 4; ++rnd) {
      int vr = rnd * 16 + w * 4 + (lane >> 4);     // pair-row 0..63
      int gg = (lane & 15) ^ (vr & 15);
      int dsrc = (vr << 1) | (gg >> 3);
      const bf16* gp = vT + ((long)(kh * HDIM + dsrc) * KVL) + ((gg & 7) << 3);
      gload16(gp, lds + 32768 + rnd * 4096 + w * 1024);
    }
  }
  __syncthreads();

  const float* mrow = mask + (size_t)(q0b + (w << 5) + l31) * KVL + (ihi << 2);

  f32x16 acc[4];
#pragma unroll
  for (int dt = 0; dt < 4; ++dt) acc[dt] = {};
  float m_run = -1e30f, l_run = 0.f;

  for (int kt = 0; kt < KVL / 64; ++kt) {
    const int cur = kt & 1;
    const int kv0 = kt << 6;

    if (kt < KVL / 64 - 1) {
      const int kv0n = kv0 + 64;
#pragma unroll
      for (int rnd = 0; rnd < 4; ++rnd) {
        int row = rnd * 16 + w * 4 + (lane >> 4);
        int cg  = (lane & 15) ^ (row & 15);
        const bf16* g = kB + (((long)(kh * KVL + kv0n + row)) << 7) + (cg << 3);
        gload16(g, lds + (cur ^ 1) * 16384 + rnd * 4096 + w * 1024);
      }
#pragma unroll
      for (int rnd = 0; rnd < 4; ++rnd) {
        int vr = rnd * 16 + w * 4 + (lane >> 4);
        int gg = (lane & 15) ^ (vr & 15);
        int dsrc = (vr << 1) | (gg >> 3);
        const bf16* gp = vT + ((long)(kh * HDIM + dsrc) * KVL) + kv0n + ((gg & 7) << 3);
        gload16(gp, lds + 32768 + (cur ^ 1) * 16384 + rnd * 4096 + w * 1024);
      }
    }

    const float* mrt = mrow + kv0;
    f32x4 mk0[4], mk1[4];
#pragma unroll
    for (int rq = 0; rq < 4; ++rq) {
      mk0[rq] = *(const f32x4*)(mrt + (rq << 3));
      mk1[rq] = *(const f32x4*)(mrt + 32 + (rq << 3));
    }

    const char* kb = lds + cur * 16384;
    f32x16 s0 = {}, s1 = {};
    const int kr0 = l31, kr1 = 32 + l31;
    __builtin_amdgcn_s_setprio(1);
#pragma unroll
    for (int s = 0; s < 8; ++s) {
      bf16x8 kf0 = *(const bf16x8*)(kb + kr0 * 256 + ((((s << 1) | ihi) ^ (kr0 & 15)) << 4));
      s0 = __builtin_amdgcn_mfma_f32_32x32x16_bf16(kf0, qf[s], s0, 0, 0, 0);
      bf16x8 kf1 = *(const bf16x8*)(kb + kr1 * 256 + ((((s << 1) | ihi) ^ (kr1 & 15)) << 4));
      s1 = __builtin_amdgcn_mfma_f32_32x32x16_bf16(kf1, qf[s], s1, 0, 0, 0);
    }
    __builtin_amdgcn_s_setprio(0);

    float p0[16], p1[16];
#pragma unroll
    for (int rq = 0; rq < 4; ++rq) {
#pragma unroll
      for (int j = 0; j < 4; ++j) {
        p0[rq * 4 + j] = s0[rq * 4 + j] + mk0[rq][j];
        p1[rq * 4 + j] = s1[rq * 4 + j] + mk1[rq][j];
      }
    }

    // ---- online softmax with defer-max (THR=8); balanced max tree ----
    float q00 = fmaxf(fmaxf(p0[0],  p0[1]),  fmaxf(p0[2],  p0[3]));
    float q01 = fmaxf(fmaxf(p0[4],  p0[5]),  fmaxf(p0[6],  p0[7]));
    float q02 = fmaxf(fmaxf(p0[8],  p0[9]),  fmaxf(p0[10], p0[11]));
    float q03 = fmaxf(fmaxf(p0[12], p0[13]), fmaxf(p0[14], p0[15]));
    float q10 = fmaxf(fmaxf(p1[0],  p1[1]),  fmaxf(p1[2],  p1[3]));
    float q11 = fmaxf(fmaxf(p1[4],  p1[5]),  fmaxf(p1[6],  p1[7]));
    float q12 = fmaxf(fmaxf(p1[8],  p1[9]),  fmaxf(p1[10], p1[11]));
    float q13 = fmaxf(fmaxf(p1[12], p1[13]), fmaxf(p1[14], p1[15]));
    float mx = fmaxf(fmaxf(fmaxf(q00, q01), fmaxf(q02, q03)),
                     fmaxf(fmaxf(q10, q11), fmaxf(q12, q13)));
    mx = fmaxf(mx, __shfl_xor(mx, 32));
    if (!__all((int)(mx - m_run <= 8.0f))) {
      float nm = fmaxf(m_run, mx);
      float al = __expf(m_run - nm);
      m_run = nm;
      l_run *= al;
#pragma unroll
      for (int dt = 0; dt < 4; ++dt) acc[dt] *= al;
    }
    float ps = 0.f;
#pragma unroll
    for (int i = 0; i < 16; ++i) { p0[i] = __expf(p0[i] - m_run); ps += p0[i]; }
#pragma unroll
    for (int i = 0; i < 16; ++i) { p1[i] = __expf(p1[i] - m_run); ps += p1[i]; }
    ps += __shfl_xor(ps, 32);
    l_run += ps;

    bf16x8 pfrag[4];
    buildfrags(p0, pfrag[0], pfrag[1]);
    buildfrags(p1, pfrag[2], pfrag[3]);

    // ---- PV: O^T[d][q] += V^T[d][kv] * P[kv][q]; V from d-paired LDS ----
    const char* vb = lds + 32768 + cur * 16384;
    const int par8 = (l31 & 1) << 3;
    __builtin_amdgcn_s_setprio(1);
#pragma unroll
    for (int dt = 0; dt < 4; ++dt) {
      const int vrow = (dt << 4) + (l31 >> 1);
      const char* vrp = vb + vrow * 256;
#pragma unroll
      for (int ks = 0; ks < 4; ++ks) {
        int c16 = par8 | (ks << 1) | ihi;
        bf16x8 vf = *(const bf16x8*)(vrp + ((c16 ^ (vrow & 15)) << 4));
        acc[dt] = __builtin_amdgcn_mfma_f32_32x32x16_bf16(vf, pfrag[ks], acc[dt], 0, 0, 0);
      }
    }
    __builtin_amdgcn_s_setprio(0);
    __syncthreads();
  }

  // ---- epilogue: normalize, LDS transpose (key &15), coalesced stores ----
  const float linv = 1.0f / l_run;
  char* ep = lds + (w << 13);      // per-warp 8KB in [0,32K)
#pragma unroll
  for (int dt = 0; dt < 4; ++dt) {
#pragma unroll
    for (int r = 0; r < 16; ++r) {
      int d = (dt << 5) + (r & 3) + ((r >> 2) << 3) + (ihi << 2);
      int byte = l31 * 256 + (((d >> 3) ^ (l31 & 15)) << 4) + ((d & 7) << 1);
      *(bf16*)(ep + byte) = (bf16)(acc[dt][r] * linv);
    }
  }
  __syncthreads();
  const size_t obase = (size_t)(q0b + (w << 5)) * DIM + h * HDIM;
#pragma unroll
  for (int i = 0; i < 8; ++i) {
    int row = (i << 2) + (lane >> 4);
    int cp  = lane & 15;
    int c   = cp ^ (row & 15);
    bf16x8 ov = *(const bf16x8*)(ep + row * 256 + (cp << 4));
    *(bf16x8*)(attnB + obase + (size_t)row * DIM + (c << 3)) = ov;
  }
}

// ------------------------------ projection GEMM ----------------------------
// C[2048x8192] = A[2048x8192] * B[8192x8192]^T. 256x128 tile, 512 blocks
// (8 m-panels x 64 n-panels) -> 2 blocks/CU. 8 waves (2m x 4n), per-wave
// output 128x32. BK=32, dbuf LDS 2x24KB = 48KB.
// LDS layout (d-pair packed, 128B rows, 8 chunk slots, key row&7):
//   A [128 rows][128B]: LDS row p holds tile-rows p (chunks 0-3) and p+128
//   (chunks 4-7), chunk c at slot c^(p&7). B [64 rows][128B]: rows p, p+64.
// Per tile: { vmcnt(3); bar; COMPUTE (10 ds_read + 16 MFMA); bar;
//             STAGE(t+2) (3 gloads) }  -- counted, never drains mid-loop.
__global__ __launch_bounds__(512, 2) void gemm_bt(
    const bf16* __restrict__ A, const bf16* __restrict__ B, float* __restrict__ C)
{
  __shared__ __align__(16) char lds[49152];
  const int tid  = threadIdx.x;
  const int lane = tid & 63;
  const int w    = tid >> 6;
  const int wm   = w >> 2;       // 0..1
  const int wn   = w & 3;        // 0..3

  const int bid = blockIdx.x;
  const int m0  = (bid >> 6) << 8;                              // 8 m-panels of 256
  const int n0  = (((bid & 7) << 3) | ((bid >> 3) & 7)) << 7;   // 64 n-panels, XCD-grouped

  // staging: thread tau -> LDS row p=(tau>>3) (+64 for A pass 1), slot tau&7,
  // chunk c = (tau&7)^((tau>>3)&7)  (same both passes since 64 = 0 mod 8)
  const int sc   = (tid & 7) ^ ((tid >> 3) & 7);
  const int arow = (tid >> 3) + ((sc >> 2) << 7);   // + 128 if c>=4
  const int brow = (tid >> 3) + ((sc >> 2) << 6);   // + 64  if c>=4
  const int kc   = (sc & 3) << 3;
  const bf16* gA = A + (long)(m0 + arow) * DIM + kc;
  const bf16* gB = B + (long)(n0 + brow) * DIM + kc;
  const long a1step = (long)64 * DIM;               // A pass 1: LDS row +64

  f32x4 acc[8][2];
#pragma unroll
  for (int i = 0; i < 8; ++i) {
    acc[i][0] = { 0.f, 0.f, 0.f, 0.f };
    acc[i][1] = { 0.f, 0.f, 0.f, 0.f };
  }

  auto STAGE = [&](int kt) {
    const long ko = (long)kt << 5;
    char* s = lds + (kt & 1) * 24576 + tid * 16;
    gload16(gA + ko, s);                    // A rows 0-63 (+hi)
    gload16(gA + a1step + ko, s + 8192);    // A rows 64-127 (+hi)
    gload16(gB + ko, s + 16384);            // B
  };

  const int g = lane >> 4;
  const int l15 = lane & 15;
  auto COMPUTE = [&](int buf) {
    const char* ab = lds + buf * 24576;
    const char* bb = ab + 16384;
    bf16x8 bfr[2];
#pragma unroll
    for (int j = 0; j < 2; ++j) {
      int n = (wn << 5) + (j << 4) + l15;
      int p = n & 63;
      int c = ((n >> 6) << 2) | g;
      bfr[j] = *(const bf16x8*)(bb + p * 128 + ((c ^ (p & 7)) << 4));
    }
    __builtin_amdgcn_s_setprio(1);
#pragma unroll
    for (int i = 0; i < 8; ++i) {
      int m = (wm << 7) + (i << 4) + l15;
      int p = m & 127;
      int c = ((m >> 7) << 2) | g;
      bf16x8 af = *(const bf16x8*)(ab + p * 128 + ((c ^ (p & 7)) << 4));
      acc[i][0] = __builtin_amdgcn_mfma_f32_16x16x32_bf16(af, bfr[0], acc[i][0], 0, 0, 0);
      acc[i][1] = __builtin_amdgcn_mfma_f32_16x16x32_bf16(af, bfr[1], acc[i][1], 0, 0, 0);
    }
    __builtin_amdgcn_s_setprio(0);
  };

  // prologue: 2 tiles in flight (6 loads/thread)
  STAGE(0);
  STAGE(1);

  // main loop: 256 K-tiles of 32
  for (int t = 0; t < 254; ++t) {
    asm volatile("s_waitcnt vmcnt(3)" ::: "memory");   // tile t's 3 loads landed
    __builtin_amdgcn_s_barrier();
    COMPUTE(t & 1);
    __builtin_amdgcn_s_barrier();                      // all waves done reading buf
    STAGE(t + 2);
  }
  // t = 254
  asm volatile("s_waitcnt vmcnt(3)" ::: "memory");
  __builtin_amdgcn_s_barrier();
  COMPUTE(0);
  __builtin_amdgcn_s_barrier();
  // t = 255
  asm volatile("s_waitcnt vmcnt(0)" ::: "memory");
  __builtin_amdgcn_s_barrier();
  COMPUTE(1);

  // epilogue: C fp32 stores
#pragma unroll
  for (int i = 0; i < 8; ++i) {
#pragma unroll
    for (int rr = 0; rr < 4; ++rr) {
      float* cp = C + (long)(m0 + (wm << 7) + (i << 4) + ((lane >> 4) << 2) + rr) * DIM
                    + n0 + (wn << 5) + l15;
      cp[0]  = acc[i][0][rr];
      cp[16] = acc[i][1][rr];
    }
  }
}

// ------------------------------- launcher ----------------------------------
extern "C" void kernel_launch(void* const* d_in, const int* in_sizes, int n_in,
                              void* d_out, int out_size, void* d_ws, size_t ws_size,
                              hipStream_t stream) {
  const float* xq     = (const float*)d_in[0];
  const float* keys   = (const float*)d_in[1];
  const float* values = (const float*)d_in[2];
  const float* mask   = (const float*)d_in[3];
  const float* wo     = (const float*)d_in[4];
  float* out = (float*)d_out;
  char* ws = (char*)d_ws;

  bf16* woB = (bf16*)ws;                                   // 128 MB
  bf16* qB  = (bf16*)(ws + 134217728ull);                  //  32 MB
  bf16* kB  = (bf16*)(ws + 134217728ull + 33554432ull);    //   4 MB
  bf16* vT  = (bf16*)(ws + 134217728ull + 37748736ull);    //   4 MB
  bf16* aB  = (bf16*)(ws + 134217728ull + 41943040ull);    //  32 MB

  cvt_f32_bf16<<<dim3(2048), dim3(256), 0, stream>>>(wo, woB, 16777216, 1.0f);
  cvt_f32_bf16<<<dim3(1024), dim3(256), 0, stream>>>(xq, qB, 4194304, 0.08838834764831845f);
  cvt_f32_bf16<<<dim3(256),  dim3(256), 0, stream>>>(keys, kB, 524288, 1.0f);
  cvt_vT_kernel<<<dim3(256), dim3(256), 0, stream>>>(values, vT);
  attn_kernel<<<dim3(1024),  dim3(256), 0, stream>>>(qB, kB, vT, mask, aB);
  gemm_bt<<<dim3(512),       dim3(512), 0, stream>>>(aB, woB, out);
}

// Round 18
// 523.360 us; speedup vs baseline: 1.0630x; 1.0630x over previous
//
#include <hip/hip_runtime.h>
#include <hip/hip_bf16.h>
#include <stdint.h>

// ---------------------------------------------------------------------------
// PytorchLlamaSDPA: GQA attention (64 q-heads, 8 kv-heads, S=KV=2048, D=128)
// + additive mask (s,t) + softmax + PV + output projection (8192x8192^T).
// bf16 MFMA, fp32 softmax/accum.
// Attention: r16 (best): 4-warp 256-thread blocks, 2 blocks/CU, swapped-QK^T,
//   K+V LDS dbuf, permlane exchange, defer-max, scale folded into Q.
// GEMM: r12-exact (best): 256x256 tile, 8 waves, BK=64, 2 LDS buffers,
//   counted vmcnt(8), two barriers/tile, XCD-co-located B panels.
// Converts: single merged kernel for the three flat fp32->bf16 passes.
// ---------------------------------------------------------------------------

typedef __bf16 bf16;
typedef __attribute__((ext_vector_type(8))) __bf16 bf16x8;
typedef __attribute__((ext_vector_type(4))) __bf16 bf16x4;
typedef __attribute__((ext_vector_type(4))) float f32x4;
typedef __attribute__((ext_vector_type(16))) float f32x16;
typedef __attribute__((ext_vector_type(4))) unsigned int u32x4;

#define N_HEADS 64
#define N_KVH   8
#define HDIM    128
#define SEQ     2048
#define KVL     2048
#define DIM     8192

__device__ __forceinline__ void gload16(const void* g, void* l) {
  __builtin_amdgcn_global_load_lds((const __attribute__((address_space(1))) void*)g,
                                   (__attribute__((address_space(3))) void*)l,
                                   16, 0, 0);
}

// pack two floats to one u32 of two bf16 (lo in bits 15:0) - pure bit ops
__device__ __forceinline__ unsigned pack2(float lo, float hi) {
  union { bf16 h; unsigned short u; } a, b;
  a.h = (bf16)lo; b.h = (bf16)hi;
  return ((unsigned)b.u << 16) | (unsigned)a.u;
}

// cross-half exchange via v_permlane32_swap_b32 (verified r11)
__device__ __forceinline__ void exch(unsigned a, unsigned b, unsigned& r0, unsigned& r1) {
  asm("v_permlane32_swap_b32 %0, %1" : "+v"(a), "+v"(b));
  r0 = a; r1 = b;
}

// Build two PV B-operand fragments (kv-slices of 16) from one 32-kv P strip.
__device__ __forceinline__ void buildfrags(const float (&p)[16], bf16x8& f0, bf16x8& f1) {
  unsigned pk0 = pack2(p[0],  p[1]),  pk1 = pack2(p[2],  p[3]);
  unsigned pk2 = pack2(p[4],  p[5]),  pk3 = pack2(p[6],  p[7]);
  unsigned pk4 = pack2(p[8],  p[9]),  pk5 = pack2(p[10], p[11]);
  unsigned pk6 = pack2(p[12], p[13]), pk7 = pack2(p[14], p[15]);
  unsigned a0, a1, b0, b1, c0, c1, d0, d1;
  exch(pk0, pk2, a0, a1);
  exch(pk1, pk3, b0, b1);
  exch(pk4, pk6, c0, c1);
  exch(pk5, pk7, d0, d1);
  u32x4 w0 = { a0, b0, a1, b1 };
  u32x4 w1 = { c0, d0, c1, d1 };
  f0 = __builtin_bit_cast(bf16x8, w0);
  f1 = __builtin_bit_cast(bf16x8, w1);
}

// ---------------- merged flat fp32 -> bf16 (wo, xq, keys) ------------------
// Region boundaries are multiples of 64K float4 -> wave-uniform branches.
#define WO_F4  16777216l
#define XQ_F4   4194304l
#define K_F4     524288l
__global__ void cvt_all(const float* __restrict__ wo, const float* __restrict__ xq,
                        const float* __restrict__ ks,
                        bf16* __restrict__ woB, bf16* __restrict__ qB,
                        bf16* __restrict__ kB) {
  long i = (long)blockIdx.x * blockDim.x + threadIdx.x;
  const long stride = (long)gridDim.x * blockDim.x;
  const long total = WO_F4 + XQ_F4 + K_F4;
  for (; i < total; i += stride) {
    const float* src; bf16* dst; float sc; long j;
    if (i < WO_F4)              { src = wo; dst = woB; sc = 1.0f; j = i; }
    else if (i < WO_F4 + XQ_F4) { src = xq; dst = qB;  sc = 0.08838834764831845f; j = i - WO_F4; }
    else                        { src = ks; dst = kB;  sc = 1.0f; j = i - WO_F4 - XQ_F4; }
    float4 v = ((const float4*)src)[j];
    bf16x4 o = { (bf16)(v.x * sc), (bf16)(v.y * sc),
                 (bf16)(v.z * sc), (bf16)(v.w * sc) };
    *(bf16x4*)(dst + j * 4) = o;
  }
}

// ------------------- values (kh,t,d) -> bf16 V^T (kh,d,t) ------------------
__global__ void cvt_vT_kernel(const float* __restrict__ v, bf16* __restrict__ vT) {
  __shared__ bf16 tile[64][132];
  const int tid = threadIdx.x;
  const int kh = blockIdx.x >> 5;
  const int t0 = (blockIdx.x & 31) << 6;
  const float* src = v + ((long)kh * KVL + t0) * HDIM;
#pragma unroll
  for (int it = 0; it < 8; ++it) {
    int q = it * 256 + tid;
    int r = q >> 5;
    int c4 = (q & 31) << 2;
    float4 val = *(const float4*)(src + (long)r * HDIM + c4);
    bf16x4 o = { (bf16)val.x, (bf16)val.y, (bf16)val.z, (bf16)val.w };
    *(bf16x4*)&tile[r][c4] = o;
  }
  __syncthreads();
  const int t = tid & 63;
  const int dbase = tid >> 6;
#pragma unroll
  for (int it = 0; it < 32; ++it) {
    int d = it * 4 + dbase;
    vT[((long)kh * HDIM + d) * KVL + t0 + t] = tile[t][d];
  }
}

// ------------------------------- attention ---------------------------------
// r16 (best): Grid 1024 = 64 heads x 16 q-blocks of 128 rows, 256 threads
// (4 warps), 2 blocks/CU. K dbuf 2x16KB [0,32K) + V d-paired dbuf 2x16KB
// [32K,64K). All LDS reads <=2-way banked. Scale pre-folded into Q.
__global__ __launch_bounds__(256, 2) void attn_kernel(
    const bf16* __restrict__ qB, const bf16* __restrict__ kB,
    const bf16* __restrict__ vT, const float* __restrict__ mask,
    bf16* __restrict__ attnB)
{
  __shared__ __align__(16) char lds[65536];

  const int tid  = threadIdx.x;
  const int lane = tid & 63;
  const int w    = tid >> 6;       // 0..3
  const int ihi  = lane >> 5;
  const int l31  = lane & 31;

  const int bid = blockIdx.x;
  const int h   = bid >> 4;
  const int q0b = (bid & 15) << 7;
  const int kh  = h >> 3;

  // ---- stage Q [128 rows][256B], key &15 ----
#pragma unroll
  for (int rnd = 0; rnd < 8; ++rnd) {
    int row = rnd * 16 + w * 4 + (lane >> 4);
    int cg  = (lane & 15) ^ (row & 15);
    const bf16* g = qB + (((long)(q0b + row) * N_HEADS + h) << 7) + (cg << 3);
    gload16(g, lds + rnd * 4096 + w * 1024);
  }
  __syncthreads();

  bf16x8 qf[8];
  {
    int qrow = (w << 5) + l31;      // 0..127
    const char* qr = lds + qrow * 256;
#pragma unroll
    for (int s = 0; s < 8; ++s)
      qf[s] = *(const bf16x8*)(qr + ((((s << 1) | ihi) ^ (qrow & 15)) << 4));
  }
  __syncthreads();   // Q area freed -> K double buffer

  // ---- stage K/V tile 0 into buffer 0 ----
  {
#pragma unroll
    for (int rnd = 0; rnd < 4; ++rnd) {
      int row = rnd * 16 + w * 4 + (lane >> 4);
      int cg  = (lane & 15) ^ (row & 15);
      const bf16* g = kB + (((long)(kh * KVL + row)) << 7) + (cg << 3);
      gload16(g, lds + rnd * 4096 + w * 1024);
    }
#pragma unroll
    for (int rnd = 0; rnd < 4; ++rnd) {
      int vr = rnd * 16 + w * 4 + (lane >> 4);     // pair-row 0..63
      int gg = (lane & 15) ^ (vr & 15);
      int dsrc = (vr << 1) | (gg >> 3);
      const bf16* gp = vT + ((long)(kh * HDIM + dsrc) * KVL) + ((gg & 7) << 3);
      gload16(gp, lds + 32768 + rnd * 4096 + w * 1024);
    }
  }
  __syncthreads();

  const float* mrow = mask + (size_t)(q0b + (w << 5) + l31) * KVL + (ihi << 2);

  f32x16 acc[4];
#pragma unroll
  for (int dt = 0; dt < 4; ++dt) acc[dt] = {};
  float m_run = -1e30f, l_run = 0.f;

  for (int kt = 0; kt < KVL / 64; ++kt) {
    const int cur = kt & 1;
    const int kv0 = kt << 6;

    if (kt < KVL / 64 - 1) {
      const int kv0n = kv0 + 64;
#pragma unroll
      for (int rnd = 0; rnd < 4; ++rnd) {
        int row = rnd * 16 + w * 4 + (lane >> 4);
        int cg  = (lane & 15) ^ (row & 15);
        const bf16* g = kB + (((long)(kh * KVL + kv0n + row)) << 7) + (cg << 3);
        gload16(g, lds + (cur ^ 1) * 16384 + rnd * 4096 + w * 1024);
      }
#pragma unroll
      for (int rnd = 0; rnd < 4; ++rnd) {
        int vr = rnd * 16 + w * 4 + (lane >> 4);
        int gg = (lane & 15) ^ (vr & 15);
        int dsrc = (vr << 1) | (gg >> 3);
        const bf16* gp = vT + ((long)(kh * HDIM + dsrc) * KVL) + kv0n + ((gg & 7) << 3);
        gload16(gp, lds + 32768 + (cur ^ 1) * 16384 + rnd * 4096 + w * 1024);
      }
    }

    const float* mrt = mrow + kv0;
    f32x4 mk0[4], mk1[4];
#pragma unroll
    for (int rq = 0; rq < 4; ++rq) {
      mk0[rq] = *(const f32x4*)(mrt + (rq << 3));
      mk1[rq] = *(const f32x4*)(mrt + 32 + (rq << 3));
    }

    const char* kb = lds + cur * 16384;
    f32x16 s0 = {}, s1 = {};
    const int kr0 = l31, kr1 = 32 + l31;
    __builtin_amdgcn_s_setprio(1);
#pragma unroll
    for (int s = 0; s < 8; ++s) {
      bf16x8 kf0 = *(const bf16x8*)(kb + kr0 * 256 + ((((s << 1) | ihi) ^ (kr0 & 15)) << 4));
      s0 = __builtin_amdgcn_mfma_f32_32x32x16_bf16(kf0, qf[s], s0, 0, 0, 0);
      bf16x8 kf1 = *(const bf16x8*)(kb + kr1 * 256 + ((((s << 1) | ihi) ^ (kr1 & 15)) << 4));
      s1 = __builtin_amdgcn_mfma_f32_32x32x16_bf16(kf1, qf[s], s1, 0, 0, 0);
    }
    __builtin_amdgcn_s_setprio(0);

    float p0[16], p1[16];
#pragma unroll
    for (int rq = 0; rq < 4; ++rq) {
#pragma unroll
      for (int j = 0; j < 4; ++j) {
        p0[rq * 4 + j] = s0[rq * 4 + j] + mk0[rq][j];
        p1[rq * 4 + j] = s1[rq * 4 + j] + mk1[rq][j];
      }
    }

    // ---- online softmax with defer-max (THR=8); balanced max tree ----
    float q00 = fmaxf(fmaxf(p0[0],  p0[1]),  fmaxf(p0[2],  p0[3]));
    float q01 = fmaxf(fmaxf(p0[4],  p0[5]),  fmaxf(p0[6],  p0[7]));
    float q02 = fmaxf(fmaxf(p0[8],  p0[9]),  fmaxf(p0[10], p0[11]));
    float q03 = fmaxf(fmaxf(p0[12], p0[13]), fmaxf(p0[14], p0[15]));
    float q10 = fmaxf(fmaxf(p1[0],  p1[1]),  fmaxf(p1[2],  p1[3]));
    float q11 = fmaxf(fmaxf(p1[4],  p1[5]),  fmaxf(p1[6],  p1[7]));
    float q12 = fmaxf(fmaxf(p1[8],  p1[9]),  fmaxf(p1[10], p1[11]));
    float q13 = fmaxf(fmaxf(p1[12], p1[13]), fmaxf(p1[14], p1[15]));
    float mx = fmaxf(fmaxf(fmaxf(q00, q01), fmaxf(q02, q03)),
                     fmaxf(fmaxf(q10, q11), fmaxf(q12, q13)));
    mx = fmaxf(mx, __shfl_xor(mx, 32));
    if (!__all((int)(mx - m_run <= 8.0f))) {
      float nm = fmaxf(m_run, mx);
      float al = __expf(m_run - nm);
      m_run = nm;
      l_run *= al;
#pragma unroll
      for (int dt = 0; dt < 4; ++dt) acc[dt] *= al;
    }
    float ps = 0.f;
#pragma unroll
    for (int i = 0; i < 16; ++i) { p0[i] = __expf(p0[i] - m_run); ps += p0[i]; }
#pragma unroll
    for (int i = 0; i < 16; ++i) { p1[i] = __expf(p1[i] - m_run); ps += p1[i]; }
    ps += __shfl_xor(ps, 32);
    l_run += ps;

    bf16x8 pfrag[4];
    buildfrags(p0, pfrag[0], pfrag[1]);
    buildfrags(p1, pfrag[2], pfrag[3]);

    // ---- PV: O^T[d][q] += V^T[d][kv] * P[kv][q]; V from d-paired LDS ----
    const char* vb = lds + 32768 + cur * 16384;
    const int par8 = (l31 & 1) << 3;
    __builtin_amdgcn_s_setprio(1);
#pragma unroll
    for (int dt = 0; dt < 4; ++dt) {
      const int vrow = (dt << 4) + (l31 >> 1);
      const char* vrp = vb + vrow * 256;
#pragma unroll
      for (int ks = 0; ks < 4; ++ks) {
        int c16 = par8 | (ks << 1) | ihi;
        bf16x8 vf = *(const bf16x8*)(vrp + ((c16 ^ (vrow & 15)) << 4));
        acc[dt] = __builtin_amdgcn_mfma_f32_32x32x16_bf16(vf, pfrag[ks], acc[dt], 0, 0, 0);
      }
    }
    __builtin_amdgcn_s_setprio(0);
    __syncthreads();
  }

  // ---- epilogue: normalize, LDS transpose (key &15), coalesced stores ----
  const float linv = 1.0f / l_run;
  char* ep = lds + (w << 13);      // per-warp 8KB in [0,32K)
#pragma unroll
  for (int dt = 0; dt < 4; ++dt) {
#pragma unroll
    for (int r = 0; r < 16; ++r) {
      int d = (dt << 5) + (r & 3) + ((r >> 2) << 3) + (ihi << 2);
      int byte = l31 * 256 + (((d >> 3) ^ (l31 & 15)) << 4) + ((d & 7) << 1);
      *(bf16*)(ep + byte) = (bf16)(acc[dt][r] * linv);
    }
  }
  __syncthreads();
  const size_t obase = (size_t)(q0b + (w << 5)) * DIM + h * HDIM;
#pragma unroll
  for (int i = 0; i < 8; ++i) {
    int row = (i << 2) + (lane >> 4);
    int cp  = lane & 15;
    int c   = cp ^ (row & 15);
    bf16x8 ov = *(const bf16x8*)(ep + row * 256 + (cp << 4));
    *(bf16x8*)(attnB + obase + (size_t)row * DIM + (c << 3)) = ov;
  }
}

// ------------------------------ projection GEMM ----------------------------
// r12-exact (best measured): 256x256 tile, 8 waves (2m x 4n), BK=64, 2 LDS
// buffers of 64KB. 128 K-tiles; prefetch depth 2; per tile:
//   { vmcnt(8); s_barrier; COMPUTE(t); s_barrier; STAGE(t+2) }.
__global__ __launch_bounds__(512, 2) void gemm_bt(
    const bf16* __restrict__ A, const bf16* __restrict__ B, float* __restrict__ C)
{
  __shared__ __align__(16) char lds[131072];
  const int tid  = threadIdx.x;
  const int lane = tid & 63;
  const int w    = tid >> 6;
  const int wm   = w >> 2;       // 0..1
  const int wn   = w & 3;        // 0..3

  const int bid = blockIdx.x;
  const int m0  = (bid >> 5) << 8;                              // 8 m-panels
  const int n0  = (((bid & 7) << 2) | ((bid >> 3) & 3)) << 8;   // 32 n-panels, XCD-grouped

  const int srow = tid >> 3;                 // 0..63
  const int sch  = (tid & 7) ^ (srow & 7);   // pre-swizzled source chunk
  const bf16* gA0 = A + (long)(m0 + srow) * DIM + (sch << 3);
  const bf16* gB0 = B + (long)(n0 + srow) * DIM + (sch << 3);
  const long rstep = (long)64 * DIM;

  f32x4 acc[8][4];
#pragma unroll
  for (int i = 0; i < 8; ++i)
#pragma unroll
    for (int j = 0; j < 4; ++j) acc[i][j] = { 0.f, 0.f, 0.f, 0.f };

  auto STAGE = [&](int kt) {
    const long ko = (long)kt << 6;
    char* s = lds + (kt & 1) * 65536 + tid * 16;
#pragma unroll
    for (int l = 0; l < 4; ++l)
      gload16(gA0 + l * rstep + ko, s + l * 8192);
#pragma unroll
    for (int l = 0; l < 4; ++l)
      gload16(gB0 + l * rstep + ko, s + 32768 + l * 8192);
  };

  const int g = lane >> 4;
  const int l15 = lane & 15;
  auto COMPUTE = [&](int buf) {
    const char* ab = lds + buf * 65536;
    const char* bb = ab + 32768;
    // B fragments held for the whole tile
    bf16x8 bfr[4][2];
#pragma unroll
    for (int j = 0; j < 4; ++j) {
      int n = (wn << 6) + (j << 4) + l15;
      const char* nr = bb + n * 128;
#pragma unroll
      for (int ks = 0; ks < 2; ++ks)
        bfr[j][ks] = *(const bf16x8*)(nr + ((((ks << 2) | g) ^ (n & 7)) << 4));
    }
    // 4 phases of 16 MFMA (2 m-frags x 4 n x 2 k-steps each)
#pragma unroll
    for (int p = 0; p < 4; ++p) {
      bf16x8 af[2][2];
#pragma unroll
      for (int e = 0; e < 2; ++e) {
        int m = (wm << 7) + (((p << 1) | e) << 4) + l15;
        const char* mr = ab + m * 128;
#pragma unroll
        for (int ks = 0; ks < 2; ++ks)
          af[e][ks] = *(const bf16x8*)(mr + ((((ks << 2) | g) ^ (m & 7)) << 4));
      }
      __builtin_amdgcn_s_setprio(1);
#pragma unroll
      for (int e = 0; e < 2; ++e)
#pragma unroll
        for (int j = 0; j < 4; ++j)
#pragma unroll
          for (int ks = 0; ks < 2; ++ks)
            acc[(p << 1) | e][j] =
              __builtin_amdgcn_mfma_f32_16x16x32_bf16(af[e][ks], bfr[j][ks],
                                                      acc[(p << 1) | e][j], 0, 0, 0);
      __builtin_amdgcn_s_setprio(0);
    }
  };

  // prologue: 2 tiles in flight (16 loads/thread)
  STAGE(0);
  STAGE(1);

  // main loop: 128 K-tiles of 64
  for (int t = 0; t < 126; ++t) {
    asm volatile("s_waitcnt vmcnt(8)" ::: "memory");   // tile t's 8 loads landed
    __builtin_amdgcn_s_barrier();
    COMPUTE(t & 1);
    __builtin_amdgcn_s_barrier();                      // all waves done reading buf
    STAGE(t + 2);
  }
  // t = 126
  asm volatile("s_waitcnt vmcnt(8)" ::: "memory");
  __builtin_amdgcn_s_barrier();
  COMPUTE(0);
  // t = 127
  asm volatile("s_waitcnt vmcnt(0)" ::: "memory");
  __builtin_amdgcn_s_barrier();
  COMPUTE(1);

  // epilogue: C fp32 stores
#pragma unroll
  for (int i = 0; i < 8; ++i) {
#pragma unroll
    for (int rr = 0; rr < 4; ++rr) {
      float* cp = C + (long)(m0 + (wm << 7) + (i << 4) + ((lane >> 4) << 2) + rr) * DIM
                    + n0 + (wn << 6) + l15;
#pragma unroll
      for (int j = 0; j < 4; ++j)
        cp[j * 16] = acc[i][j][rr];
    }
  }
}

// ------------------------------- launcher ----------------------------------
extern "C" void kernel_launch(void* const* d_in, const int* in_sizes, int n_in,
                              void* d_out, int out_size, void* d_ws, size_t ws_size,
                              hipStream_t stream) {
  const float* xq     = (const float*)d_in[0];
  const float* keys   = (const float*)d_in[1];
  const float* values = (const float*)d_in[2];
  const float* mask   = (const float*)d_in[3];
  const float* wo     = (const float*)d_in[4];
  float* out = (float*)d_out;
  char* ws = (char*)d_ws;

  bf16* woB = (bf16*)ws;                                   // 128 MB
  bf16* qB  = (bf16*)(ws + 134217728ull);                  //  32 MB
  bf16* kB  = (bf16*)(ws + 134217728ull + 33554432ull);    //   4 MB
  bf16* vT  = (bf16*)(ws + 134217728ull + 37748736ull);    //   4 MB
  bf16* aB  = (bf16*)(ws + 134217728ull + 41943040ull);    //  32 MB

  cvt_all<<<dim3(2560), dim3(256), 0, stream>>>(wo, xq, keys, woB, qB, kB);
  cvt_vT_kernel<<<dim3(256), dim3(256), 0, stream>>>(values, vT);
  attn_kernel<<<dim3(1024),  dim3(256), 0, stream>>>(qB, kB, vT, mask, aB);
  gemm_bt<<<dim3(256),       dim3(512), 0, stream>>>(aB, woB, out);
}

// Round 19
// 514.974 us; speedup vs baseline: 1.0803x; 1.0163x over previous
//
#include <hip/hip_runtime.h>
#include <hip/hip_bf16.h>
#include <stdint.h>

// ---------------------------------------------------------------------------
// PytorchLlamaSDPA: GQA attention (64 q-heads, 8 kv-heads, S=KV=2048, D=128)
// + additive mask (s,t) + softmax + PV + output projection (8192x8192^T).
// bf16 MFMA, fp32 softmax/accum.
// Attention: r16 (best): 4-warp 256-thread blocks, 2 blocks/CU.
// GEMM: r12 geometry (256x256, BK=64, 2 bufs, depth-2 counted vmcnt) with
//   4-phase ring-staged schedule: per-phase barriers, staging interleaved
//   into dead regions, vmcnt(6) steady state (never drains mid-loop).
// Converts: merged flat fp32->bf16 kernel + V^T transpose kernel.
// ---------------------------------------------------------------------------

typedef __bf16 bf16;
typedef __attribute__((ext_vector_type(8))) __bf16 bf16x8;
typedef __attribute__((ext_vector_type(4))) __bf16 bf16x4;
typedef __attribute__((ext_vector_type(4))) float f32x4;
typedef __attribute__((ext_vector_type(16))) float f32x16;
typedef __attribute__((ext_vector_type(4))) unsigned int u32x4;

#define N_HEADS 64
#define N_KVH   8
#define HDIM    128
#define SEQ     2048
#define KVL     2048
#define DIM     8192

__device__ __forceinline__ void gload16(const void* g, void* l) {
  __builtin_amdgcn_global_load_lds((const __attribute__((address_space(1))) void*)g,
                                   (__attribute__((address_space(3))) void*)l,
                                   16, 0, 0);
}

// pack two floats to one u32 of two bf16 (lo in bits 15:0) - pure bit ops
__device__ __forceinline__ unsigned pack2(float lo, float hi) {
  union { bf16 h; unsigned short u; } a, b;
  a.h = (bf16)lo; b.h = (bf16)hi;
  return ((unsigned)b.u << 16) | (unsigned)a.u;
}

// cross-half exchange via v_permlane32_swap_b32 (verified r11)
__device__ __forceinline__ void exch(unsigned a, unsigned b, unsigned& r0, unsigned& r1) {
  asm("v_permlane32_swap_b32 %0, %1" : "+v"(a), "+v"(b));
  r0 = a; r1 = b;
}

// Build two PV B-operand fragments (kv-slices of 16) from one 32-kv P strip.
__device__ __forceinline__ void buildfrags(const float (&p)[16], bf16x8& f0, bf16x8& f1) {
  unsigned pk0 = pack2(p[0],  p[1]),  pk1 = pack2(p[2],  p[3]);
  unsigned pk2 = pack2(p[4],  p[5]),  pk3 = pack2(p[6],  p[7]);
  unsigned pk4 = pack2(p[8],  p[9]),  pk5 = pack2(p[10], p[11]);
  unsigned pk6 = pack2(p[12], p[13]), pk7 = pack2(p[14], p[15]);
  unsigned a0, a1, b0, b1, c0, c1, d0, d1;
  exch(pk0, pk2, a0, a1);
  exch(pk1, pk3, b0, b1);
  exch(pk4, pk6, c0, c1);
  exch(pk5, pk7, d0, d1);
  u32x4 w0 = { a0, b0, a1, b1 };
  u32x4 w1 = { c0, d0, c1, d1 };
  f0 = __builtin_bit_cast(bf16x8, w0);
  f1 = __builtin_bit_cast(bf16x8, w1);
}

// ---------------- merged flat fp32 -> bf16 (wo, xq, keys) ------------------
#define WO_F4  16777216l
#define XQ_F4   4194304l
#define K_F4     524288l
__global__ void cvt_all(const float* __restrict__ wo, const float* __restrict__ xq,
                        const float* __restrict__ ks,
                        bf16* __restrict__ woB, bf16* __restrict__ qB,
                        bf16* __restrict__ kB) {
  long i = (long)blockIdx.x * blockDim.x + threadIdx.x;
  const long stride = (long)gridDim.x * blockDim.x;
  const long total = WO_F4 + XQ_F4 + K_F4;
  for (; i < total; i += stride) {
    const float* src; bf16* dst; float sc; long j;
    if (i < WO_F4)              { src = wo; dst = woB; sc = 1.0f; j = i; }
    else if (i < WO_F4 + XQ_F4) { src = xq; dst = qB;  sc = 0.08838834764831845f; j = i - WO_F4; }
    else                        { src = ks; dst = kB;  sc = 1.0f; j = i - WO_F4 - XQ_F4; }
    float4 v = ((const float4*)src)[j];
    bf16x4 o = { (bf16)(v.x * sc), (bf16)(v.y * sc),
                 (bf16)(v.z * sc), (bf16)(v.w * sc) };
    *(bf16x4*)(dst + j * 4) = o;
  }
}

// ------------------- values (kh,t,d) -> bf16 V^T (kh,d,t) ------------------
__global__ void cvt_vT_kernel(const float* __restrict__ v, bf16* __restrict__ vT) {
  __shared__ bf16 tile[64][132];
  const int tid = threadIdx.x;
  const int kh = blockIdx.x >> 5;
  const int t0 = (blockIdx.x & 31) << 6;
  const float* src = v + ((long)kh * KVL + t0) * HDIM;
#pragma unroll
  for (int it = 0; it < 8; ++it) {
    int q = it * 256 + tid;
    int r = q >> 5;
    int c4 = (q & 31) << 2;
    float4 val = *(const float4*)(src + (long)r * HDIM + c4);
    bf16x4 o = { (bf16)val.x, (bf16)val.y, (bf16)val.z, (bf16)val.w };
    *(bf16x4*)&tile[r][c4] = o;
  }
  __syncthreads();
  const int t = tid & 63;
  const int dbase = tid >> 6;
#pragma unroll
  for (int it = 0; it < 32; ++it) {
    int d = it * 4 + dbase;
    vT[((long)kh * HDIM + d) * KVL + t0 + t] = tile[t][d];
  }
}

// ------------------------------- attention ---------------------------------
// r16 (best): Grid 1024 = 64 heads x 16 q-blocks of 128 rows, 256 threads
// (4 warps), 2 blocks/CU. K dbuf 2x16KB [0,32K) + V d-paired dbuf 2x16KB
// [32K,64K). All LDS reads <=2-way banked. Scale pre-folded into Q.
__global__ __launch_bounds__(256, 2) void attn_kernel(
    const bf16* __restrict__ qB, const bf16* __restrict__ kB,
    const bf16* __restrict__ vT, const float* __restrict__ mask,
    bf16* __restrict__ attnB)
{
  __shared__ __align__(16) char lds[65536];

  const int tid  = threadIdx.x;
  const int lane = tid & 63;
  const int w    = tid >> 6;       // 0..3
  const int ihi  = lane >> 5;
  const int l31  = lane & 31;

  const int bid = blockIdx.x;
  const int h   = bid >> 4;
  const int q0b = (bid & 15) << 7;
  const int kh  = h >> 3;

  // ---- stage Q [128 rows][256B], key &15 ----
#pragma unroll
  for (int rnd = 0; rnd < 8; ++rnd) {
    int row = rnd * 16 + w * 4 + (lane >> 4);
    int cg  = (lane & 15) ^ (row & 15);
    const bf16* g = qB + (((long)(q0b + row) * N_HEADS + h) << 7) + (cg << 3);
    gload16(g, lds + rnd * 4096 + w * 1024);
  }
  __syncthreads();

  bf16x8 qf[8];
  {
    int qrow = (w << 5) + l31;      // 0..127
    const char* qr = lds + qrow * 256;
#pragma unroll
    for (int s = 0; s < 8; ++s)
      qf[s] = *(const bf16x8*)(qr + ((((s << 1) | ihi) ^ (qrow & 15)) << 4));
  }
  __syncthreads();   // Q area freed -> K double buffer

  // ---- stage K/V tile 0 into buffer 0 ----
  {
#pragma unroll
    for (int rnd = 0; rnd < 4; ++rnd) {
      int row = rnd * 16 + w * 4 + (lane >> 4);
      int cg  = (lane & 15) ^ (row & 15);
      const bf16* g = kB + (((long)(kh * KVL + row)) << 7) + (cg << 3);
      gload16(g, lds + rnd * 4096 + w * 1024);
    }
#pragma unroll
    for (int rnd = 0; rnd < 4; ++rnd) {
      int vr = rnd * 16 + w * 4 + (lane >> 4);     // pair-row 0..63
      int gg = (lane & 15) ^ (vr & 15);
      int dsrc = (vr << 1) | (gg >> 3);
      const bf16* gp = vT + ((long)(kh * HDIM + dsrc) * KVL) + ((gg & 7) << 3);
      gload16(gp, lds + 32768 + rnd * 4096 + w * 1024);
    }
  }
  __syncthreads();

  const float* mrow = mask + (size_t)(q0b + (w << 5) + l31) * KVL + (ihi << 2);

  f32x16 acc[4];
#pragma unroll
  for (int dt = 0; dt < 4; ++dt) acc[dt] = {};
  float m_run = -1e30f, l_run = 0.f;

  for (int kt = 0; kt < KVL / 64; ++kt) {
    const int cur = kt & 1;
    const int kv0 = kt << 6;

    if (kt < KVL / 64 - 1) {
      const int kv0n = kv0 + 64;
#pragma unroll
      for (int rnd = 0; rnd < 4; ++rnd) {
        int row = rnd * 16 + w * 4 + (lane >> 4);
        int cg  = (lane & 15) ^ (row & 15);
        const bf16* g = kB + (((long)(kh * KVL + kv0n + row)) << 7) + (cg << 3);
        gload16(g, lds + (cur ^ 1) * 16384 + rnd * 4096 + w * 1024);
      }
#pragma unroll
      for (int rnd = 0; rnd < 4; ++rnd) {
        int vr = rnd * 16 + w * 4 + (lane >> 4);
        int gg = (lane & 15) ^ (vr & 15);
        int dsrc = (vr << 1) | (gg >> 3);
        const bf16* gp = vT + ((long)(kh * HDIM + dsrc) * KVL) + kv0n + ((gg & 7) << 3);
        gload16(gp, lds + 32768 + (cur ^ 1) * 16384 + rnd * 4096 + w * 1024);
      }
    }

    const float* mrt = mrow + kv0;
    f32x4 mk0[4], mk1[4];
#pragma unroll
    for (int rq = 0; rq < 4; ++rq) {
      mk0[rq] = *(const f32x4*)(mrt + (rq << 3));
      mk1[rq] = *(const f32x4*)(mrt + 32 + (rq << 3));
    }

    const char* kb = lds + cur * 16384;
    f32x16 s0 = {}, s1 = {};
    const int kr0 = l31, kr1 = 32 + l31;
    __builtin_amdgcn_s_setprio(1);
#pragma unroll
    for (int s = 0; s < 8; ++s) {
      bf16x8 kf0 = *(const bf16x8*)(kb + kr0 * 256 + ((((s << 1) | ihi) ^ (kr0 & 15)) << 4));
      s0 = __builtin_amdgcn_mfma_f32_32x32x16_bf16(kf0, qf[s], s0, 0, 0, 0);
      bf16x8 kf1 = *(const bf16x8*)(kb + kr1 * 256 + ((((s << 1) | ihi) ^ (kr1 & 15)) << 4));
      s1 = __builtin_amdgcn_mfma_f32_32x32x16_bf16(kf1, qf[s], s1, 0, 0, 0);
    }
    __builtin_amdgcn_s_setprio(0);

    float p0[16], p1[16];
#pragma unroll
    for (int rq = 0; rq < 4; ++rq) {
#pragma unroll
      for (int j = 0; j < 4; ++j) {
        p0[rq * 4 + j] = s0[rq * 4 + j] + mk0[rq][j];
        p1[rq * 4 + j] = s1[rq * 4 + j] + mk1[rq][j];
      }
    }

    // ---- online softmax with defer-max (THR=8); balanced max tree ----
    float q00 = fmaxf(fmaxf(p0[0],  p0[1]),  fmaxf(p0[2],  p0[3]));
    float q01 = fmaxf(fmaxf(p0[4],  p0[5]),  fmaxf(p0[6],  p0[7]));
    float q02 = fmaxf(fmaxf(p0[8],  p0[9]),  fmaxf(p0[10], p0[11]));
    float q03 = fmaxf(fmaxf(p0[12], p0[13]), fmaxf(p0[14], p0[15]));
    float q10 = fmaxf(fmaxf(p1[0],  p1[1]),  fmaxf(p1[2],  p1[3]));
    float q11 = fmaxf(fmaxf(p1[4],  p1[5]),  fmaxf(p1[6],  p1[7]));
    float q12 = fmaxf(fmaxf(p1[8],  p1[9]),  fmaxf(p1[10], p1[11]));
    float q13 = fmaxf(fmaxf(p1[12], p1[13]), fmaxf(p1[14], p1[15]));
    float mx = fmaxf(fmaxf(fmaxf(q00, q01), fmaxf(q02, q03)),
                     fmaxf(fmaxf(q10, q11), fmaxf(q12, q13)));
    mx = fmaxf(mx, __shfl_xor(mx, 32));
    if (!__all((int)(mx - m_run <= 8.0f))) {
      float nm = fmaxf(m_run, mx);
      float al = __expf(m_run - nm);
      m_run = nm;
      l_run *= al;
#pragma unroll
      for (int dt = 0; dt < 4; ++dt) acc[dt] *= al;
    }
    float ps = 0.f;
#pragma unroll
    for (int i = 0; i < 16; ++i) { p0[i] = __expf(p0[i] - m_run); ps += p0[i]; }
#pragma unroll
    for (int i = 0; i < 16; ++i) { p1[i] = __expf(p1[i] - m_run); ps += p1[i]; }
    ps += __shfl_xor(ps, 32);
    l_run += ps;

    bf16x8 pfrag[4];
    buildfrags(p0, pfrag[0], pfrag[1]);
    buildfrags(p1, pfrag[2], pfrag[3]);

    // ---- PV: O^T[d][q] += V^T[d][kv] * P[kv][q]; V from d-paired LDS ----
    const char* vb = lds + 32768 + cur * 16384;
    const int par8 = (l31 & 1) << 3;
    __builtin_amdgcn_s_setprio(1);
#pragma unroll
    for (int dt = 0; dt < 4; ++dt) {
      const int vrow = (dt << 4) + (l31 >> 1);
      const char* vrp = vb + vrow * 256;
#pragma unroll
      for (int ks = 0; ks < 4; ++ks) {
        int c16 = par8 | (ks << 1) | ihi;
        bf16x8 vf = *(const bf16x8*)(vrp + ((c16 ^ (vrow & 15)) << 4));
        acc[dt] = __builtin_amdgcn_mfma_f32_32x32x16_bf16(vf, pfrag[ks], acc[dt], 0, 0, 0);
      }
    }
    __builtin_amdgcn_s_setprio(0);
    __syncthreads();
  }

  // ---- epilogue: normalize, LDS transpose (key &15), coalesced stores ----
  const float linv = 1.0f / l_run;
  char* ep = lds + (w << 13);      // per-warp 8KB in [0,32K)
#pragma unroll
  for (int dt = 0; dt < 4; ++dt) {
#pragma unroll
    for (int r = 0; r < 16; ++r) {
      int d = (dt << 5) + (r & 3) + ((r >> 2) << 3) + (ihi << 2);
      int byte = l31 * 256 + (((d >> 3) ^ (l31 & 15)) << 4) + ((d & 7) << 1);
      *(bf16*)(ep + byte) = (bf16)(acc[dt][r] * linv);
    }
  }
  __syncthreads();
  const size_t obase = (size_t)(q0b + (w << 5)) * DIM + h * HDIM;
#pragma unroll
  for (int i = 0; i < 8; ++i) {
    int row = (i << 2) + (lane >> 4);
    int cp  = lane & 15;
    int c   = cp ^ (row & 15);
    bf16x8 ov = *(const bf16x8*)(ep + row * 256 + (cp << 4));
    *(bf16x8*)(attnB + obase + (size_t)row * DIM + (c << 3)) = ov;
  }
}

// ------------------------------ projection GEMM ----------------------------
// 256x256 tile, 8 waves (2m x 4n), BK=64, 2 LDS buffers of 64KB, depth-2.
// 4-phase ring-staged schedule. Liveness (from the read pattern):
//   B fully read in phase 0 -> stage B(t+2) halves in phases 1,2.
//   A quarters l=0,2 (rows 0-63 / 128-191) die after phase 1 -> phases 2,3.
//   A quarters l=1,3 die at tile end -> staged at next tile's phase 0.
// vmcnt at tile t phase 0: outstanding = 6 partial loads of tile t+1
//   -> vmcnt(6) (t=0: 8 from prologue; t=127: 0 tail drain).
__global__ __launch_bounds__(512, 2) void gemm_bt(
    const bf16* __restrict__ A, const bf16* __restrict__ B, float* __restrict__ C)
{
  __shared__ __align__(16) char lds[131072];
  const int tid  = threadIdx.x;
  const int lane = tid & 63;
  const int w    = tid >> 6;
  const int wm   = w >> 2;       // 0..1
  const int wn   = w & 3;        // 0..3

  const int bid = blockIdx.x;
  const int m0  = (bid >> 5) << 8;                              // 8 m-panels
  const int n0  = (((bid & 7) << 2) | ((bid >> 3) & 3)) << 8;   // 32 n-panels, XCD-grouped

  const int srow = tid >> 3;                 // 0..63
  const int sch  = (tid & 7) ^ (srow & 7);   // pre-swizzled source chunk
  const bf16* gA0 = A + (long)(m0 + srow) * DIM + (sch << 3);
  const bf16* gB0 = B + (long)(n0 + srow) * DIM + (sch << 3);
  const long rstep = (long)64 * DIM;

  f32x4 acc[8][4];
#pragma unroll
  for (int i = 0; i < 8; ++i)
#pragma unroll
    for (int j = 0; j < 4; ++j) acc[i][j] = { 0.f, 0.f, 0.f, 0.f };

  auto stageA = [&](int kt, int l) {
    const long ko = (long)kt << 6;
    char* s = lds + (kt & 1) * 65536 + tid * 16;
    gload16(gA0 + l * rstep + ko, s + l * 8192);
  };
  auto stageB = [&](int kt, int l) {
    const long ko = (long)kt << 6;
    char* s = lds + (kt & 1) * 65536 + 32768 + tid * 16;
    gload16(gB0 + l * rstep + ko, s + l * 8192);
  };

  const int g = lane >> 4;
  const int l15 = lane & 15;

  for (int t = 0; t < 128; ++t) {
    const char* ab = lds + (t & 1) * 65536;
    const char* bb = ab + 32768;

    if (t == 0) {
      // prologue: stage tiles 0,1 fully (16 loads/thread)
#pragma unroll
      for (int l = 0; l < 4; ++l) { stageA(0, l); }
#pragma unroll
      for (int l = 0; l < 4; ++l) { stageB(0, l); }
#pragma unroll
      for (int l = 0; l < 4; ++l) { stageA(1, l); }
#pragma unroll
      for (int l = 0; l < 4; ++l) { stageB(1, l); }
      asm volatile("s_waitcnt vmcnt(8)" ::: "memory");
    } else if (t == 127) {
      asm volatile("s_waitcnt vmcnt(0)" ::: "memory");
    } else {
      asm volatile("s_waitcnt vmcnt(6)" ::: "memory");
    }
    __builtin_amdgcn_s_barrier();

    // ---- phase 0: all B fragments + A phase-0 fragments; A-tail of t+1 ----
    bf16x8 bfr[4][2];
#pragma unroll
    for (int j = 0; j < 4; ++j) {
      int n = (wn << 6) + (j << 4) + l15;
      const char* nr = bb + n * 128;
#pragma unroll
      for (int ks = 0; ks < 2; ++ks)
        bfr[j][ks] = *(const bf16x8*)(nr + ((((ks << 2) | g) ^ (n & 7)) << 4));
    }
    {
      bf16x8 af[2][2];
#pragma unroll
      for (int e = 0; e < 2; ++e) {
        int m = (wm << 7) + (e << 4) + l15;
        const char* mr = ab + m * 128;
#pragma unroll
        for (int ks = 0; ks < 2; ++ks)
          af[e][ks] = *(const bf16x8*)(mr + ((((ks << 2) | g) ^ (m & 7)) << 4));
      }
      if (t >= 1 && t <= 126) { stageA(t + 1, 1); stageA(t + 1, 3); }
      __builtin_amdgcn_s_setprio(1);
#pragma unroll
      for (int e = 0; e < 2; ++e)
#pragma unroll
        for (int j = 0; j < 4; ++j)
#pragma unroll
          for (int ks = 0; ks < 2; ++ks)
            acc[e][j] = __builtin_amdgcn_mfma_f32_16x16x32_bf16(
                af[e][ks], bfr[j][ks], acc[e][j], 0, 0, 0);
      __builtin_amdgcn_s_setprio(0);
    }

    // ---- phases 1..3: A fragments per phase; ring-stage t+2 ----
#pragma unroll
    for (int p = 1; p < 4; ++p) {
      __builtin_amdgcn_s_barrier();
      bf16x8 af[2][2];
#pragma unroll
      for (int e = 0; e < 2; ++e) {
        int m = (wm << 7) + (((p << 1) | e) << 4) + l15;
        const char* mr = ab + m * 128;
#pragma unroll
        for (int ks = 0; ks < 2; ++ks)
          af[e][ks] = *(const bf16x8*)(mr + ((((ks << 2) | g) ^ (m & 7)) << 4));
      }
      if (t + 2 < 128) {
        if (p == 1)      { stageB(t + 2, 0); stageB(t + 2, 1); }
        else if (p == 2) { stageB(t + 2, 2); stageB(t + 2, 3); stageA(t + 2, 0); }
        else             { stageA(t + 2, 2); }
      }
      __builtin_amdgcn_s_setprio(1);
#pragma unroll
      for (int e = 0; e < 2; ++e)
#pragma unroll
        for (int j = 0; j < 4; ++j)
#pragma unroll
          for (int ks = 0; ks < 2; ++ks)
            acc[(p << 1) | e][j] = __builtin_amdgcn_mfma_f32_16x16x32_bf16(
                af[e][ks], bfr[j][ks], acc[(p << 1) | e][j], 0, 0, 0);
      __builtin_amdgcn_s_setprio(0);
    }
    __builtin_amdgcn_s_barrier();   // tile-end: A l=1,3 regions die here
  }

  // epilogue: C fp32 stores
#pragma unroll
  for (int i = 0; i < 8; ++i) {
#pragma unroll
    for (int rr = 0; rr < 4; ++rr) {
      float* cp = C + (long)(m0 + (wm << 7) + (i << 4) + ((lane >> 4) << 2) + rr) * DIM
                    + n0 + (wn << 6) + l15;
#pragma unroll
      for (int j = 0; j < 4; ++j)
        cp[j * 16] = acc[i][j][rr];
    }
  }
}

// ------------------------------- launcher ----------------------------------
extern "C" void kernel_launch(void* const* d_in, const int* in_sizes, int n_in,
                              void* d_out, int out_size, void* d_ws, size_t ws_size,
                              hipStream_t stream) {
  const float* xq     = (const float*)d_in[0];
  const float* keys   = (const float*)d_in[1];
  const float* values = (const float*)d_in[2];
  const float* mask   = (const float*)d_in[3];
  const float* wo     = (const float*)d_in[4];
  float* out = (float*)d_out;
  char* ws = (char*)d_ws;

  bf16* woB = (bf16*)ws;                                   // 128 MB
  bf16* qB  = (bf16*)(ws + 134217728ull);                  //  32 MB
  bf16* kB  = (bf16*)(ws + 134217728ull + 33554432ull);    //   4 MB
  bf16* vT  = (bf16*)(ws + 134217728ull + 37748736ull);    //   4 MB
  bf16* aB  = (bf16*)(ws + 134217728ull + 41943040ull);    //  32 MB

  cvt_all<<<dim3(2560), dim3(256), 0, stream>>>(wo, xq, keys, woB, qB, kB);
  cvt_vT_kernel<<<dim3(256), dim3(256), 0, stream>>>(values, vT);
  attn_kernel<<<dim3(1024),  dim3(256), 0, stream>>>(qB, kB, vT, mask, aB);
  gemm_bt<<<dim3(256),       dim3(512), 0, stream>>>(aB, woB, out);
}

// Round 20
// 511.185 us; speedup vs baseline: 1.0883x; 1.0074x over previous
//
#include <hip/hip_runtime.h>
#include <hip/hip_bf16.h>
#include <stdint.h>

// ---------------------------------------------------------------------------
// PytorchLlamaSDPA: GQA attention (64 q-heads, 8 kv-heads, S=KV=2048, D=128)
// + additive mask (s,t) + softmax + PV + output projection (8192x8192^T).
// bf16 MFMA, fp32 softmax/accum.
// Attention: r16 (best): 4-warp 256-thread blocks, 2 blocks/CU.
// GEMM: r19 4-phase ring-staged schedule (best), peeled prologue/epilogue,
//   staging issued ahead of each phase's ds_reads.
// Converts: merged flat fp32->bf16 kernel + V^T transpose kernel.
// ---------------------------------------------------------------------------

typedef __bf16 bf16;
typedef __attribute__((ext_vector_type(8))) __bf16 bf16x8;
typedef __attribute__((ext_vector_type(4))) __bf16 bf16x4;
typedef __attribute__((ext_vector_type(4))) float f32x4;
typedef __attribute__((ext_vector_type(16))) float f32x16;
typedef __attribute__((ext_vector_type(4))) unsigned int u32x4;

#define N_HEADS 64
#define N_KVH   8
#define HDIM    128
#define SEQ     2048
#define KVL     2048
#define DIM     8192

__device__ __forceinline__ void gload16(const void* g, void* l) {
  __builtin_amdgcn_global_load_lds((const __attribute__((address_space(1))) void*)g,
                                   (__attribute__((address_space(3))) void*)l,
                                   16, 0, 0);
}

// pack two floats to one u32 of two bf16 (lo in bits 15:0) - pure bit ops
__device__ __forceinline__ unsigned pack2(float lo, float hi) {
  union { bf16 h; unsigned short u; } a, b;
  a.h = (bf16)lo; b.h = (bf16)hi;
  return ((unsigned)b.u << 16) | (unsigned)a.u;
}

// cross-half exchange via v_permlane32_swap_b32 (verified r11)
__device__ __forceinline__ void exch(unsigned a, unsigned b, unsigned& r0, unsigned& r1) {
  asm("v_permlane32_swap_b32 %0, %1" : "+v"(a), "+v"(b));
  r0 = a; r1 = b;
}

// Build two PV B-operand fragments (kv-slices of 16) from one 32-kv P strip.
__device__ __forceinline__ void buildfrags(const float (&p)[16], bf16x8& f0, bf16x8& f1) {
  unsigned pk0 = pack2(p[0],  p[1]),  pk1 = pack2(p[2],  p[3]);
  unsigned pk2 = pack2(p[4],  p[5]),  pk3 = pack2(p[6],  p[7]);
  unsigned pk4 = pack2(p[8],  p[9]),  pk5 = pack2(p[10], p[11]);
  unsigned pk6 = pack2(p[12], p[13]), pk7 = pack2(p[14], p[15]);
  unsigned a0, a1, b0, b1, c0, c1, d0, d1;
  exch(pk0, pk2, a0, a1);
  exch(pk1, pk3, b0, b1);
  exch(pk4, pk6, c0, c1);
  exch(pk5, pk7, d0, d1);
  u32x4 w0 = { a0, b0, a1, b1 };
  u32x4 w1 = { c0, d0, c1, d1 };
  f0 = __builtin_bit_cast(bf16x8, w0);
  f1 = __builtin_bit_cast(bf16x8, w1);
}

// ---------------- merged flat fp32 -> bf16 (wo, xq, keys) ------------------
#define WO_F4  16777216l
#define XQ_F4   4194304l
#define K_F4     524288l
__global__ void cvt_all(const float* __restrict__ wo, const float* __restrict__ xq,
                        const float* __restrict__ ks,
                        bf16* __restrict__ woB, bf16* __restrict__ qB,
                        bf16* __restrict__ kB) {
  long i = (long)blockIdx.x * blockDim.x + threadIdx.x;
  const long stride = (long)gridDim.x * blockDim.x;
  const long total = WO_F4 + XQ_F4 + K_F4;
  for (; i < total; i += stride) {
    const float* src; bf16* dst; float sc; long j;
    if (i < WO_F4)              { src = wo; dst = woB; sc = 1.0f; j = i; }
    else if (i < WO_F4 + XQ_F4) { src = xq; dst = qB;  sc = 0.08838834764831845f; j = i - WO_F4; }
    else                        { src = ks; dst = kB;  sc = 1.0f; j = i - WO_F4 - XQ_F4; }
    float4 v = ((const float4*)src)[j];
    bf16x4 o = { (bf16)(v.x * sc), (bf16)(v.y * sc),
                 (bf16)(v.z * sc), (bf16)(v.w * sc) };
    *(bf16x4*)(dst + j * 4) = o;
  }
}

// ------------------- values (kh,t,d) -> bf16 V^T (kh,d,t) ------------------
__global__ void cvt_vT_kernel(const float* __restrict__ v, bf16* __restrict__ vT) {
  __shared__ bf16 tile[64][132];
  const int tid = threadIdx.x;
  const int kh = blockIdx.x >> 5;
  const int t0 = (blockIdx.x & 31) << 6;
  const float* src = v + ((long)kh * KVL + t0) * HDIM;
#pragma unroll
  for (int it = 0; it < 8; ++it) {
    int q = it * 256 + tid;
    int r = q >> 5;
    int c4 = (q & 31) << 2;
    float4 val = *(const float4*)(src + (long)r * HDIM + c4);
    bf16x4 o = { (bf16)val.x, (bf16)val.y, (bf16)val.z, (bf16)val.w };
    *(bf16x4*)&tile[r][c4] = o;
  }
  __syncthreads();
  const int t = tid & 63;
  const int dbase = tid >> 6;
#pragma unroll
  for (int it = 0; it < 32; ++it) {
    int d = it * 4 + dbase;
    vT[((long)kh * HDIM + d) * KVL + t0 + t] = tile[t][d];
  }
}

// ------------------------------- attention ---------------------------------
// r16 (best): Grid 1024 = 64 heads x 16 q-blocks of 128 rows, 256 threads
// (4 warps), 2 blocks/CU. K dbuf 2x16KB [0,32K) + V d-paired dbuf 2x16KB
// [32K,64K). All LDS reads <=2-way banked. Scale pre-folded into Q.
__global__ __launch_bounds__(256, 2) void attn_kernel(
    const bf16* __restrict__ qB, const bf16* __restrict__ kB,
    const bf16* __restrict__ vT, const float* __restrict__ mask,
    bf16* __restrict__ attnB)
{
  __shared__ __align__(16) char lds[65536];

  const int tid  = threadIdx.x;
  const int lane = tid & 63;
  const int w    = tid >> 6;       // 0..3
  const int ihi  = lane >> 5;
  const int l31  = lane & 31;

  const int bid = blockIdx.x;
  const int h   = bid >> 4;
  const int q0b = (bid & 15) << 7;
  const int kh  = h >> 3;

  // ---- stage Q [128 rows][256B], key &15 ----
#pragma unroll
  for (int rnd = 0; rnd < 8; ++rnd) {
    int row = rnd * 16 + w * 4 + (lane >> 4);
    int cg  = (lane & 15) ^ (row & 15);
    const bf16* g = qB + (((long)(q0b + row) * N_HEADS + h) << 7) + (cg << 3);
    gload16(g, lds + rnd * 4096 + w * 1024);
  }
  __syncthreads();

  bf16x8 qf[8];
  {
    int qrow = (w << 5) + l31;      // 0..127
    const char* qr = lds + qrow * 256;
#pragma unroll
    for (int s = 0; s < 8; ++s)
      qf[s] = *(const bf16x8*)(qr + ((((s << 1) | ihi) ^ (qrow & 15)) << 4));
  }
  __syncthreads();   // Q area freed -> K double buffer

  // ---- stage K/V tile 0 into buffer 0 ----
  {
#pragma unroll
    for (int rnd = 0; rnd < 4; ++rnd) {
      int row = rnd * 16 + w * 4 + (lane >> 4);
      int cg  = (lane & 15) ^ (row & 15);
      const bf16* g = kB + (((long)(kh * KVL + row)) << 7) + (cg << 3);
      gload16(g, lds + rnd * 4096 + w * 1024);
    }
#pragma unroll
    for (int rnd = 0; rnd < 4; ++rnd) {
      int vr = rnd * 16 + w * 4 + (lane >> 4);     // pair-row 0..63
      int gg = (lane & 15) ^ (vr & 15);
      int dsrc = (vr << 1) | (gg >> 3);
      const bf16* gp = vT + ((long)(kh * HDIM + dsrc) * KVL) + ((gg & 7) << 3);
      gload16(gp, lds + 32768 + rnd * 4096 + w * 1024);
    }
  }
  __syncthreads();

  const float* mrow = mask + (size_t)(q0b + (w << 5) + l31) * KVL + (ihi << 2);

  f32x16 acc[4];
#pragma unroll
  for (int dt = 0; dt < 4; ++dt) acc[dt] = {};
  float m_run = -1e30f, l_run = 0.f;

  for (int kt = 0; kt < KVL / 64; ++kt) {
    const int cur = kt & 1;
    const int kv0 = kt << 6;

    if (kt < KVL / 64 - 1) {
      const int kv0n = kv0 + 64;
#pragma unroll
      for (int rnd = 0; rnd < 4; ++rnd) {
        int row = rnd * 16 + w * 4 + (lane >> 4);
        int cg  = (lane & 15) ^ (row & 15);
        const bf16* g = kB + (((long)(kh * KVL + kv0n + row)) << 7) + (cg << 3);
        gload16(g, lds + (cur ^ 1) * 16384 + rnd * 4096 + w * 1024);
      }
#pragma unroll
      for (int rnd = 0; rnd < 4; ++rnd) {
        int vr = rnd * 16 + w * 4 + (lane >> 4);
        int gg = (lane & 15) ^ (vr & 15);
        int dsrc = (vr << 1) | (gg >> 3);
        const bf16* gp = vT + ((long)(kh * HDIM + dsrc) * KVL) + kv0n + ((gg & 7) << 3);
        gload16(gp, lds + 32768 + (cur ^ 1) * 16384 + rnd * 4096 + w * 1024);
      }
    }

    const float* mrt = mrow + kv0;
    f32x4 mk0[4], mk1[4];
#pragma unroll
    for (int rq = 0; rq < 4; ++rq) {
      mk0[rq] = *(const f32x4*)(mrt + (rq << 3));
      mk1[rq] = *(const f32x4*)(mrt + 32 + (rq << 3));
    }

    const char* kb = lds + cur * 16384;
    f32x16 s0 = {}, s1 = {};
    const int kr0 = l31, kr1 = 32 + l31;
    __builtin_amdgcn_s_setprio(1);
#pragma unroll
    for (int s = 0; s < 8; ++s) {
      bf16x8 kf0 = *(const bf16x8*)(kb + kr0 * 256 + ((((s << 1) | ihi) ^ (kr0 & 15)) << 4));
      s0 = __builtin_amdgcn_mfma_f32_32x32x16_bf16(kf0, qf[s], s0, 0, 0, 0);
      bf16x8 kf1 = *(const bf16x8*)(kb + kr1 * 256 + ((((s << 1) | ihi) ^ (kr1 & 15)) << 4));
      s1 = __builtin_amdgcn_mfma_f32_32x32x16_bf16(kf1, qf[s], s1, 0, 0, 0);
    }
    __builtin_amdgcn_s_setprio(0);

    float p0[16], p1[16];
#pragma unroll
    for (int rq = 0; rq < 4; ++rq) {
#pragma unroll
      for (int j = 0; j < 4; ++j) {
        p0[rq * 4 + j] = s0[rq * 4 + j] + mk0[rq][j];
        p1[rq * 4 + j] = s1[rq * 4 + j] + mk1[rq][j];
      }
    }

    // ---- online softmax with defer-max (THR=8); balanced max tree ----
    float q00 = fmaxf(fmaxf(p0[0],  p0[1]),  fmaxf(p0[2],  p0[3]));
    float q01 = fmaxf(fmaxf(p0[4],  p0[5]),  fmaxf(p0[6],  p0[7]));
    float q02 = fmaxf(fmaxf(p0[8],  p0[9]),  fmaxf(p0[10], p0[11]));
    float q03 = fmaxf(fmaxf(p0[12], p0[13]), fmaxf(p0[14], p0[15]));
    float q10 = fmaxf(fmaxf(p1[0],  p1[1]),  fmaxf(p1[2],  p1[3]));
    float q11 = fmaxf(fmaxf(p1[4],  p1[5]),  fmaxf(p1[6],  p1[7]));
    float q12 = fmaxf(fmaxf(p1[8],  p1[9]),  fmaxf(p1[10], p1[11]));
    float q13 = fmaxf(fmaxf(p1[12], p1[13]), fmaxf(p1[14], p1[15]));
    float mx = fmaxf(fmaxf(fmaxf(q00, q01), fmaxf(q02, q03)),
                     fmaxf(fmaxf(q10, q11), fmaxf(q12, q13)));
    mx = fmaxf(mx, __shfl_xor(mx, 32));
    if (!__all((int)(mx - m_run <= 8.0f))) {
      float nm = fmaxf(m_run, mx);
      float al = __expf(m_run - nm);
      m_run = nm;
      l_run *= al;
#pragma unroll
      for (int dt = 0; dt < 4; ++dt) acc[dt] *= al;
    }
    float ps = 0.f;
#pragma unroll
    for (int i = 0; i < 16; ++i) { p0[i] = __expf(p0[i] - m_run); ps += p0[i]; }
#pragma unroll
    for (int i = 0; i < 16; ++i) { p1[i] = __expf(p1[i] - m_run); ps += p1[i]; }
    ps += __shfl_xor(ps, 32);
    l_run += ps;

    bf16x8 pfrag[4];
    buildfrags(p0, pfrag[0], pfrag[1]);
    buildfrags(p1, pfrag[2], pfrag[3]);

    // ---- PV: O^T[d][q] += V^T[d][kv] * P[kv][q]; V from d-paired LDS ----
    const char* vb = lds + 32768 + cur * 16384;
    const int par8 = (l31 & 1) << 3;
    __builtin_amdgcn_s_setprio(1);
#pragma unroll
    for (int dt = 0; dt < 4; ++dt) {
      const int vrow = (dt << 4) + (l31 >> 1);
      const char* vrp = vb + vrow * 256;
#pragma unroll
      for (int ks = 0; ks < 4; ++ks) {
        int c16 = par8 | (ks << 1) | ihi;
        bf16x8 vf = *(const bf16x8*)(vrp + ((c16 ^ (vrow & 15)) << 4));
        acc[dt] = __builtin_amdgcn_mfma_f32_32x32x16_bf16(vf, pfrag[ks], acc[dt], 0, 0, 0);
      }
    }
    __builtin_amdgcn_s_setprio(0);
    __syncthreads();
  }

  // ---- epilogue: normalize, LDS transpose (key &15), coalesced stores ----
  const float linv = 1.0f / l_run;
  char* ep = lds + (w << 13);      // per-warp 8KB in [0,32K)
#pragma unroll
  for (int dt = 0; dt < 4; ++dt) {
#pragma unroll
    for (int r = 0; r < 16; ++r) {
      int d = (dt << 5) + (r & 3) + ((r >> 2) << 3) + (ihi << 2);
      int byte = l31 * 256 + (((d >> 3) ^ (l31 & 15)) << 4) + ((d & 7) << 1);
      *(bf16*)(ep + byte) = (bf16)(acc[dt][r] * linv);
    }
  }
  __syncthreads();
  const size_t obase = (size_t)(q0b + (w << 5)) * DIM + h * HDIM;
#pragma unroll
  for (int i = 0; i < 8; ++i) {
    int row = (i << 2) + (lane >> 4);
    int cp  = lane & 15;
    int c   = cp ^ (row & 15);
    bf16x8 ov = *(const bf16x8*)(ep + row * 256 + (cp << 4));
    *(bf16x8*)(attnB + obase + (size_t)row * DIM + (c << 3)) = ov;
  }
}

// ------------------------------ projection GEMM ----------------------------
// r19 4-phase ring-staged schedule (best), peeled:
//   B dies after phase 0 -> stage B(t+2) in phases 1,2.
//   A quarters l=0,2 die after phase 1 -> stage in phases 2,3.
//   A l=1,3 die at tile end -> staged at next tile's phase 0.
// Steady-state wait: vmcnt(6). Staging issued before each phase's ds_reads.
__global__ __launch_bounds__(512, 2) void gemm_bt(
    const bf16* __restrict__ A, const bf16* __restrict__ B, float* __restrict__ C)
{
  __shared__ __align__(16) char lds[131072];
  const int tid  = threadIdx.x;
  const int lane = tid & 63;
  const int w    = tid >> 6;
  const int wm   = w >> 2;       // 0..1
  const int wn   = w & 3;        // 0..3

  const int bid = blockIdx.x;
  const int m0  = (bid >> 5) << 8;                              // 8 m-panels
  const int n0  = (((bid & 7) << 2) | ((bid >> 3) & 3)) << 8;   // 32 n-panels, XCD-grouped

  const int srow = tid >> 3;                 // 0..63
  const int sch  = (tid & 7) ^ (srow & 7);   // pre-swizzled source chunk
  const bf16* gA0 = A + (long)(m0 + srow) * DIM + (sch << 3);
  const bf16* gB0 = B + (long)(n0 + srow) * DIM + (sch << 3);
  const long rstep = (long)64 * DIM;

  f32x4 acc[8][4];
#pragma unroll
  for (int i = 0; i < 8; ++i)
#pragma unroll
    for (int j = 0; j < 4; ++j) acc[i][j] = { 0.f, 0.f, 0.f, 0.f };

  auto stageA = [&](int kt, int l) {
    const long ko = (long)kt << 6;
    char* s = lds + (kt & 1) * 65536 + tid * 16;
    gload16(gA0 + l * rstep + ko, s + l * 8192);
  };
  auto stageB = [&](int kt, int l) {
    const long ko = (long)kt << 6;
    char* s = lds + (kt & 1) * 65536 + 32768 + tid * 16;
    gload16(gB0 + l * rstep + ko, s + l * 8192);
  };

  const int g = lane >> 4;
  const int l15 = lane & 15;

  // TILE body: stage0 = A(t+1) tail in phase 0 (steady only); stage t+2 in
  // phases 1..3 when in range.
  auto TILE = [&](int t, bool tailA, bool st2) {
    const char* ab = lds + (t & 1) * 65536;
    const char* bb = ab + 32768;

    // ---- phase 0: stage A(t+1) l=1,3; read all B + A rows p0; 16 MFMA ----
    if (tailA) { stageA(t + 1, 1); stageA(t + 1, 3); }
    bf16x8 bfr[4][2];
#pragma unroll
    for (int j = 0; j < 4; ++j) {
      int n = (wn << 6) + (j << 4) + l15;
      const char* nr = bb + n * 128;
#pragma unroll
      for (int ks = 0; ks < 2; ++ks)
        bfr[j][ks] = *(const bf16x8*)(nr + ((((ks << 2) | g) ^ (n & 7)) << 4));
    }
    {
      bf16x8 af[2][2];
#pragma unroll
      for (int e = 0; e < 2; ++e) {
        int m = (wm << 7) + (e << 4) + l15;
        const char* mr = ab + m * 128;
#pragma unroll
        for (int ks = 0; ks < 2; ++ks)
          af[e][ks] = *(const bf16x8*)(mr + ((((ks << 2) | g) ^ (m & 7)) << 4));
      }
      __builtin_amdgcn_s_setprio(1);
#pragma unroll
      for (int e = 0; e < 2; ++e)
#pragma unroll
        for (int j = 0; j < 4; ++j)
#pragma unroll
          for (int ks = 0; ks < 2; ++ks)
            acc[e][j] = __builtin_amdgcn_mfma_f32_16x16x32_bf16(
                af[e][ks], bfr[j][ks], acc[e][j], 0, 0, 0);
      __builtin_amdgcn_s_setprio(0);
    }

    // ---- phases 1..3 ----
#pragma unroll
    for (int p = 1; p < 4; ++p) {
      __builtin_amdgcn_s_barrier();
      if (st2) {
        if (p == 1)      { stageB(t + 2, 0); stageB(t + 2, 1); }
        else if (p == 2) { stageB(t + 2, 2); stageB(t + 2, 3); stageA(t + 2, 0); }
        else             { stageA(t + 2, 2); }
      }
      bf16x8 af[2][2];
#pragma unroll
      for (int e = 0; e < 2; ++e) {
        int m = (wm << 7) + (((p << 1) | e) << 4) + l15;
        const char* mr = ab + m * 128;
#pragma unroll
        for (int ks = 0; ks < 2; ++ks)
          af[e][ks] = *(const bf16x8*)(mr + ((((ks << 2) | g) ^ (m & 7)) << 4));
      }
      __builtin_amdgcn_s_setprio(1);
#pragma unroll
      for (int e = 0; e < 2; ++e)
#pragma unroll
        for (int j = 0; j < 4; ++j)
#pragma unroll
          for (int ks = 0; ks < 2; ++ks)
            acc[(p << 1) | e][j] = __builtin_amdgcn_mfma_f32_16x16x32_bf16(
                af[e][ks], bfr[j][ks], acc[(p << 1) | e][j], 0, 0, 0);
      __builtin_amdgcn_s_setprio(0);
    }
    __builtin_amdgcn_s_barrier();   // tile-end: A l=1,3 regions die here
  };

  // prologue: stage tiles 0,1 fully (16 loads/thread)
#pragma unroll
  for (int l = 0; l < 4; ++l) stageA(0, l);
#pragma unroll
  for (int l = 0; l < 4; ++l) stageB(0, l);
#pragma unroll
  for (int l = 0; l < 4; ++l) stageA(1, l);
#pragma unroll
  for (int l = 0; l < 4; ++l) stageB(1, l);

  // t = 0 (tile 1's A-tail already staged by prologue)
  asm volatile("s_waitcnt vmcnt(8)" ::: "memory");
  __builtin_amdgcn_s_barrier();
  TILE(0, false, true);

  // steady state: t = 1..125 (stage A-tail of t+1 and tile t+2)
  for (int t = 1; t < 126; ++t) {
    asm volatile("s_waitcnt vmcnt(6)" ::: "memory");
    __builtin_amdgcn_s_barrier();
    TILE(t, true, true);
  }

  // t = 126 (stage A-tail of 127; no t+2)
  asm volatile("s_waitcnt vmcnt(6)" ::: "memory");
  __builtin_amdgcn_s_barrier();
  TILE(126, true, false);

  // t = 127 (drain)
  asm volatile("s_waitcnt vmcnt(0)" ::: "memory");
  __builtin_amdgcn_s_barrier();
  TILE(127, false, false);

  // epilogue: C fp32 stores
#pragma unroll
  for (int i = 0; i < 8; ++i) {
#pragma unroll
    for (int rr = 0; rr < 4; ++rr) {
      float* cp = C + (long)(m0 + (wm << 7) + (i << 4) + ((lane >> 4) << 2) + rr) * DIM
                    + n0 + (wn << 6) + l15;
#pragma unroll
      for (int j = 0; j < 4; ++j)
        cp[j * 16] = acc[i][j][rr];
    }
  }
}

// ------------------------------- launcher ----------------------------------
extern "C" void kernel_launch(void* const* d_in, const int* in_sizes, int n_in,
                              void* d_out, int out_size, void* d_ws, size_t ws_size,
                              hipStream_t stream) {
  const float* xq     = (const float*)d_in[0];
  const float* keys   = (const float*)d_in[1];
  const float* values = (const float*)d_in[2];
  const float* mask   = (const float*)d_in[3];
  const float* wo     = (const float*)d_in[4];
  float* out = (float*)d_out;
  char* ws = (char*)d_ws;

  bf16* woB = (bf16*)ws;                                   // 128 MB
  bf16* qB  = (bf16*)(ws + 134217728ull);                  //  32 MB
  bf16* kB  = (bf16*)(ws + 134217728ull + 33554432ull);    //   4 MB
  bf16* vT  = (bf16*)(ws + 134217728ull + 37748736ull);    //   4 MB
  bf16* aB  = (bf16*)(ws + 134217728ull + 41943040ull);    //  32 MB

  cvt_all<<<dim3(2560), dim3(256), 0, stream>>>(wo, xq, keys, woB, qB, kB);
  cvt_vT_kernel<<<dim3(256), dim3(256), 0, stream>>>(values, vT);
  attn_kernel<<<dim3(1024),  dim3(256), 0, stream>>>(qB, kB, vT, mask, aB);
  gemm_bt<<<dim3(256),       dim3(512), 0, stream>>>(aB, woB, out);
}

// Round 21
// 506.579 us; speedup vs baseline: 1.0982x; 1.0091x over previous
//
#include <hip/hip_runtime.h>
#include <hip/hip_bf16.h>
#include <stdint.h>

// ---------------------------------------------------------------------------
// PytorchLlamaSDPA: GQA attention (64 q-heads, 8 kv-heads, S=KV=2048, D=128)
// + additive mask (s,t) + softmax + PV + output projection (8192x8192^T).
// bf16 MFMA, fp32 softmax/accum.
// Attention: r16 (best): 4-warp 256-thread blocks, 2 blocks/CU.
// GEMM: r20 4-phase ring-staged schedule + register double-buffered A
//   fragments (af(p+1) read under phase p's MFMA cluster).
// Converts: merged flat fp32->bf16 kernel + V^T transpose kernel.
// ---------------------------------------------------------------------------

typedef __bf16 bf16;
typedef __attribute__((ext_vector_type(8))) __bf16 bf16x8;
typedef __attribute__((ext_vector_type(4))) __bf16 bf16x4;
typedef __attribute__((ext_vector_type(4))) float f32x4;
typedef __attribute__((ext_vector_type(16))) float f32x16;
typedef __attribute__((ext_vector_type(4))) unsigned int u32x4;

#define N_HEADS 64
#define N_KVH   8
#define HDIM    128
#define SEQ     2048
#define KVL     2048
#define DIM     8192

__device__ __forceinline__ void gload16(const void* g, void* l) {
  __builtin_amdgcn_global_load_lds((const __attribute__((address_space(1))) void*)g,
                                   (__attribute__((address_space(3))) void*)l,
                                   16, 0, 0);
}

// pack two floats to one u32 of two bf16 (lo in bits 15:0) - pure bit ops
__device__ __forceinline__ unsigned pack2(float lo, float hi) {
  union { bf16 h; unsigned short u; } a, b;
  a.h = (bf16)lo; b.h = (bf16)hi;
  return ((unsigned)b.u << 16) | (unsigned)a.u;
}

// cross-half exchange via v_permlane32_swap_b32 (verified r11)
__device__ __forceinline__ void exch(unsigned a, unsigned b, unsigned& r0, unsigned& r1) {
  asm("v_permlane32_swap_b32 %0, %1" : "+v"(a), "+v"(b));
  r0 = a; r1 = b;
}

// Build two PV B-operand fragments (kv-slices of 16) from one 32-kv P strip.
__device__ __forceinline__ void buildfrags(const float (&p)[16], bf16x8& f0, bf16x8& f1) {
  unsigned pk0 = pack2(p[0],  p[1]),  pk1 = pack2(p[2],  p[3]);
  unsigned pk2 = pack2(p[4],  p[5]),  pk3 = pack2(p[6],  p[7]);
  unsigned pk4 = pack2(p[8],  p[9]),  pk5 = pack2(p[10], p[11]);
  unsigned pk6 = pack2(p[12], p[13]), pk7 = pack2(p[14], p[15]);
  unsigned a0, a1, b0, b1, c0, c1, d0, d1;
  exch(pk0, pk2, a0, a1);
  exch(pk1, pk3, b0, b1);
  exch(pk4, pk6, c0, c1);
  exch(pk5, pk7, d0, d1);
  u32x4 w0 = { a0, b0, a1, b1 };
  u32x4 w1 = { c0, d0, c1, d1 };
  f0 = __builtin_bit_cast(bf16x8, w0);
  f1 = __builtin_bit_cast(bf16x8, w1);
}

// ---------------- merged flat fp32 -> bf16 (wo, xq, keys) ------------------
#define WO_F4  16777216l
#define XQ_F4   4194304l
#define K_F4     524288l
__global__ void cvt_all(const float* __restrict__ wo, const float* __restrict__ xq,
                        const float* __restrict__ ks,
                        bf16* __restrict__ woB, bf16* __restrict__ qB,
                        bf16* __restrict__ kB) {
  long i = (long)blockIdx.x * blockDim.x + threadIdx.x;
  const long stride = (long)gridDim.x * blockDim.x;
  const long total = WO_F4 + XQ_F4 + K_F4;
  for (; i < total; i += stride) {
    const float* src; bf16* dst; float sc; long j;
    if (i < WO_F4)              { src = wo; dst = woB; sc = 1.0f; j = i; }
    else if (i < WO_F4 + XQ_F4) { src = xq; dst = qB;  sc = 0.08838834764831845f; j = i - WO_F4; }
    else                        { src = ks; dst = kB;  sc = 1.0f; j = i - WO_F4 - XQ_F4; }
    float4 v = ((const float4*)src)[j];
    bf16x4 o = { (bf16)(v.x * sc), (bf16)(v.y * sc),
                 (bf16)(v.z * sc), (bf16)(v.w * sc) };
    *(bf16x4*)(dst + j * 4) = o;
  }
}

// ------------------- values (kh,t,d) -> bf16 V^T (kh,d,t) ------------------
__global__ void cvt_vT_kernel(const float* __restrict__ v, bf16* __restrict__ vT) {
  __shared__ bf16 tile[64][132];
  const int tid = threadIdx.x;
  const int kh = blockIdx.x >> 5;
  const int t0 = (blockIdx.x & 31) << 6;
  const float* src = v + ((long)kh * KVL + t0) * HDIM;
#pragma unroll
  for (int it = 0; it < 8; ++it) {
    int q = it * 256 + tid;
    int r = q >> 5;
    int c4 = (q & 31) << 2;
    float4 val = *(const float4*)(src + (long)r * HDIM + c4);
    bf16x4 o = { (bf16)val.x, (bf16)val.y, (bf16)val.z, (bf16)val.w };
    *(bf16x4*)&tile[r][c4] = o;
  }
  __syncthreads();
  const int t = tid & 63;
  const int dbase = tid >> 6;
#pragma unroll
  for (int it = 0; it < 32; ++it) {
    int d = it * 4 + dbase;
    vT[((long)kh * HDIM + d) * KVL + t0 + t] = tile[t][d];
  }
}

// ------------------------------- attention ---------------------------------
// r16 (best): Grid 1024 = 64 heads x 16 q-blocks of 128 rows, 256 threads
// (4 warps), 2 blocks/CU. K dbuf 2x16KB [0,32K) + V d-paired dbuf 2x16KB
// [32K,64K). All LDS reads <=2-way banked. Scale pre-folded into Q.
__global__ __launch_bounds__(256, 2) void attn_kernel(
    const bf16* __restrict__ qB, const bf16* __restrict__ kB,
    const bf16* __restrict__ vT, const float* __restrict__ mask,
    bf16* __restrict__ attnB)
{
  __shared__ __align__(16) char lds[65536];

  const int tid  = threadIdx.x;
  const int lane = tid & 63;
  const int w    = tid >> 6;       // 0..3
  const int ihi  = lane >> 5;
  const int l31  = lane & 31;

  const int bid = blockIdx.x;
  const int h   = bid >> 4;
  const int q0b = (bid & 15) << 7;
  const int kh  = h >> 3;

  // ---- stage Q [128 rows][256B], key &15 ----
#pragma unroll
  for (int rnd = 0; rnd < 8; ++rnd) {
    int row = rnd * 16 + w * 4 + (lane >> 4);
    int cg  = (lane & 15) ^ (row & 15);
    const bf16* g = qB + (((long)(q0b + row) * N_HEADS + h) << 7) + (cg << 3);
    gload16(g, lds + rnd * 4096 + w * 1024);
  }
  __syncthreads();

  bf16x8 qf[8];
  {
    int qrow = (w << 5) + l31;      // 0..127
    const char* qr = lds + qrow * 256;
#pragma unroll
    for (int s = 0; s < 8; ++s)
      qf[s] = *(const bf16x8*)(qr + ((((s << 1) | ihi) ^ (qrow & 15)) << 4));
  }
  __syncthreads();   // Q area freed -> K double buffer

  // ---- stage K/V tile 0 into buffer 0 ----
  {
#pragma unroll
    for (int rnd = 0; rnd < 4; ++rnd) {
      int row = rnd * 16 + w * 4 + (lane >> 4);
      int cg  = (lane & 15) ^ (row & 15);
      const bf16* g = kB + (((long)(kh * KVL + row)) << 7) + (cg << 3);
      gload16(g, lds + rnd * 4096 + w * 1024);
    }
#pragma unroll
    for (int rnd = 0; rnd < 4; ++rnd) {
      int vr = rnd * 16 + w * 4 + (lane >> 4);     // pair-row 0..63
      int gg = (lane & 15) ^ (vr & 15);
      int dsrc = (vr << 1) | (gg >> 3);
      const bf16* gp = vT + ((long)(kh * HDIM + dsrc) * KVL) + ((gg & 7) << 3);
      gload16(gp, lds + 32768 + rnd * 4096 + w * 1024);
    }
  }
  __syncthreads();

  const float* mrow = mask + (size_t)(q0b + (w << 5) + l31) * KVL + (ihi << 2);

  f32x16 acc[4];
#pragma unroll
  for (int dt = 0; dt < 4; ++dt) acc[dt] = {};
  float m_run = -1e30f, l_run = 0.f;

  for (int kt = 0; kt < KVL / 64; ++kt) {
    const int cur = kt & 1;
    const int kv0 = kt << 6;

    if (kt < KVL / 64 - 1) {
      const int kv0n = kv0 + 64;
#pragma unroll
      for (int rnd = 0; rnd < 4; ++rnd) {
        int row = rnd * 16 + w * 4 + (lane >> 4);
        int cg  = (lane & 15) ^ (row & 15);
        const bf16* g = kB + (((long)(kh * KVL + kv0n + row)) << 7) + (cg << 3);
        gload16(g, lds + (cur ^ 1) * 16384 + rnd * 4096 + w * 1024);
      }
#pragma unroll
      for (int rnd = 0; rnd < 4; ++rnd) {
        int vr = rnd * 16 + w * 4 + (lane >> 4);
        int gg = (lane & 15) ^ (vr & 15);
        int dsrc = (vr << 1) | (gg >> 3);
        const bf16* gp = vT + ((long)(kh * HDIM + dsrc) * KVL) + kv0n + ((gg & 7) << 3);
        gload16(gp, lds + 32768 + (cur ^ 1) * 16384 + rnd * 4096 + w * 1024);
      }
    }

    const float* mrt = mrow + kv0;
    f32x4 mk0[4], mk1[4];
#pragma unroll
    for (int rq = 0; rq < 4; ++rq) {
      mk0[rq] = *(const f32x4*)(mrt + (rq << 3));
      mk1[rq] = *(const f32x4*)(mrt + 32 + (rq << 3));
    }

    const char* kb = lds + cur * 16384;
    f32x16 s0 = {}, s1 = {};
    const int kr0 = l31, kr1 = 32 + l31;
    __builtin_amdgcn_s_setprio(1);
#pragma unroll
    for (int s = 0; s < 8; ++s) {
      bf16x8 kf0 = *(const bf16x8*)(kb + kr0 * 256 + ((((s << 1) | ihi) ^ (kr0 & 15)) << 4));
      s0 = __builtin_amdgcn_mfma_f32_32x32x16_bf16(kf0, qf[s], s0, 0, 0, 0);
      bf16x8 kf1 = *(const bf16x8*)(kb + kr1 * 256 + ((((s << 1) | ihi) ^ (kr1 & 15)) << 4));
      s1 = __builtin_amdgcn_mfma_f32_32x32x16_bf16(kf1, qf[s], s1, 0, 0, 0);
    }
    __builtin_amdgcn_s_setprio(0);

    float p0[16], p1[16];
#pragma unroll
    for (int rq = 0; rq < 4; ++rq) {
#pragma unroll
      for (int j = 0; j < 4; ++j) {
        p0[rq * 4 + j] = s0[rq * 4 + j] + mk0[rq][j];
        p1[rq * 4 + j] = s1[rq * 4 + j] + mk1[rq][j];
      }
    }

    // ---- online softmax with defer-max (THR=8); balanced max tree ----
    float q00 = fmaxf(fmaxf(p0[0],  p0[1]),  fmaxf(p0[2],  p0[3]));
    float q01 = fmaxf(fmaxf(p0[4],  p0[5]),  fmaxf(p0[6],  p0[7]));
    float q02 = fmaxf(fmaxf(p0[8],  p0[9]),  fmaxf(p0[10], p0[11]));
    float q03 = fmaxf(fmaxf(p0[12], p0[13]), fmaxf(p0[14], p0[15]));
    float q10 = fmaxf(fmaxf(p1[0],  p1[1]),  fmaxf(p1[2],  p1[3]));
    float q11 = fmaxf(fmaxf(p1[4],  p1[5]),  fmaxf(p1[6],  p1[7]));
    float q12 = fmaxf(fmaxf(p1[8],  p1[9]),  fmaxf(p1[10], p1[11]));
    float q13 = fmaxf(fmaxf(p1[12], p1[13]), fmaxf(p1[14], p1[15]));
    float mx = fmaxf(fmaxf(fmaxf(q00, q01), fmaxf(q02, q03)),
                     fmaxf(fmaxf(q10, q11), fmaxf(q12, q13)));
    mx = fmaxf(mx, __shfl_xor(mx, 32));
    if (!__all((int)(mx - m_run <= 8.0f))) {
      float nm = fmaxf(m_run, mx);
      float al = __expf(m_run - nm);
      m_run = nm;
      l_run *= al;
#pragma unroll
      for (int dt = 0; dt < 4; ++dt) acc[dt] *= al;
    }
    float ps = 0.f;
#pragma unroll
    for (int i = 0; i < 16; ++i) { p0[i] = __expf(p0[i] - m_run); ps += p0[i]; }
#pragma unroll
    for (int i = 0; i < 16; ++i) { p1[i] = __expf(p1[i] - m_run); ps += p1[i]; }
    ps += __shfl_xor(ps, 32);
    l_run += ps;

    bf16x8 pfrag[4];
    buildfrags(p0, pfrag[0], pfrag[1]);
    buildfrags(p1, pfrag[2], pfrag[3]);

    // ---- PV: O^T[d][q] += V^T[d][kv] * P[kv][q]; V from d-paired LDS ----
    const char* vb = lds + 32768 + cur * 16384;
    const int par8 = (l31 & 1) << 3;
    __builtin_amdgcn_s_setprio(1);
#pragma unroll
    for (int dt = 0; dt < 4; ++dt) {
      const int vrow = (dt << 4) + (l31 >> 1);
      const char* vrp = vb + vrow * 256;
#pragma unroll
      for (int ks = 0; ks < 4; ++ks) {
        int c16 = par8 | (ks << 1) | ihi;
        bf16x8 vf = *(const bf16x8*)(vrp + ((c16 ^ (vrow & 15)) << 4));
        acc[dt] = __builtin_amdgcn_mfma_f32_32x32x16_bf16(vf, pfrag[ks], acc[dt], 0, 0, 0);
      }
    }
    __builtin_amdgcn_s_setprio(0);
    __syncthreads();
  }

  // ---- epilogue: normalize, LDS transpose (key &15), coalesced stores ----
  const float linv = 1.0f / l_run;
  char* ep = lds + (w << 13);      // per-warp 8KB in [0,32K)
#pragma unroll
  for (int dt = 0; dt < 4; ++dt) {
#pragma unroll
    for (int r = 0; r < 16; ++r) {
      int d = (dt << 5) + (r & 3) + ((r >> 2) << 3) + (ihi << 2);
      int byte = l31 * 256 + (((d >> 3) ^ (l31 & 15)) << 4) + ((d & 7) << 1);
      *(bf16*)(ep + byte) = (bf16)(acc[dt][r] * linv);
    }
  }
  __syncthreads();
  const size_t obase = (size_t)(q0b + (w << 5)) * DIM + h * HDIM;
#pragma unroll
  for (int i = 0; i < 8; ++i) {
    int row = (i << 2) + (lane >> 4);
    int cp  = lane & 15;
    int c   = cp ^ (row & 15);
    bf16x8 ov = *(const bf16x8*)(ep + row * 256 + (cp << 4));
    *(bf16x8*)(attnB + obase + (size_t)row * DIM + (c << 3)) = ov;
  }
}

// ------------------------------ projection GEMM ----------------------------
// r20 4-phase ring-staged schedule + register-double-buffered A fragments:
//   af(p+1) is read during phase p's MFMA cluster (current tile's LDS is
//   never written during the tile -> read-ahead is race-free).
//   B dies after phase 0 -> stage B(t+2) in phases 1,2.
//   A quarters l=0,2 die after phase 1 -> stage in phases 2,3.
//   A l=1,3 die at tile end -> staged at next tile's phase 0.
// Steady-state wait: vmcnt(6).
__global__ __launch_bounds__(512, 2) void gemm_bt(
    const bf16* __restrict__ A, const bf16* __restrict__ B, float* __restrict__ C)
{
  __shared__ __align__(16) char lds[131072];
  const int tid  = threadIdx.x;
  const int lane = tid & 63;
  const int w    = tid >> 6;
  const int wm   = w >> 2;       // 0..1
  const int wn   = w & 3;        // 0..3

  const int bid = blockIdx.x;
  const int m0  = (bid >> 5) << 8;                              // 8 m-panels
  const int n0  = (((bid & 7) << 2) | ((bid >> 3) & 3)) << 8;   // 32 n-panels, XCD-grouped

  const int srow = tid >> 3;                 // 0..63
  const int sch  = (tid & 7) ^ (srow & 7);   // pre-swizzled source chunk
  const bf16* gA0 = A + (long)(m0 + srow) * DIM + (sch << 3);
  const bf16* gB0 = B + (long)(n0 + srow) * DIM + (sch << 3);
  const long rstep = (long)64 * DIM;

  f32x4 acc[8][4];
#pragma unroll
  for (int i = 0; i < 8; ++i)
#pragma unroll
    for (int j = 0; j < 4; ++j) acc[i][j] = { 0.f, 0.f, 0.f, 0.f };

  auto stageA = [&](int kt, int l) {
    const long ko = (long)kt << 6;
    char* s = lds + (kt & 1) * 65536 + tid * 16;
    gload16(gA0 + l * rstep + ko, s + l * 8192);
  };
  auto stageB = [&](int kt, int l) {
    const long ko = (long)kt << 6;
    char* s = lds + (kt & 1) * 65536 + 32768 + tid * 16;
    gload16(gB0 + l * rstep + ko, s + l * 8192);
  };

  const int g = lane >> 4;
  const int l15 = lane & 15;

  auto TILE = [&](int t, bool tailA, bool st2) {
    const char* ab = lds + (t & 1) * 65536;
    const char* bb = ab + 32768;

    bf16x8 bfr[4][2];
    bf16x8 af[2][2][2];   // [slot][e][ks], slot = phase & 1

    // read A fragments for phase p into slot s
    auto RDAF = [&](int p, int s) {
#pragma unroll
      for (int e = 0; e < 2; ++e) {
        int m = (wm << 7) + (((p << 1) | e) << 4) + l15;
        const char* mr = ab + m * 128;
#pragma unroll
        for (int ks = 0; ks < 2; ++ks)
          af[s][e][ks] = *(const bf16x8*)(mr + ((((ks << 2) | g) ^ (m & 7)) << 4));
      }
    };
    auto MM = [&](int p, int s) {
      __builtin_amdgcn_s_setprio(1);
#pragma unroll
      for (int e = 0; e < 2; ++e)
#pragma unroll
        for (int j = 0; j < 4; ++j)
#pragma unroll
          for (int ks = 0; ks < 2; ++ks)
            acc[(p << 1) | e][j] = __builtin_amdgcn_mfma_f32_16x16x32_bf16(
                af[s][e][ks], bfr[j][ks], acc[(p << 1) | e][j], 0, 0, 0);
      __builtin_amdgcn_s_setprio(0);
    };

    // ---- phase 0: stage A(t+1) tail; read B, af(0), af(1); MFMA(0) ----
    if (tailA) { stageA(t + 1, 1); stageA(t + 1, 3); }
#pragma unroll
    for (int j = 0; j < 4; ++j) {
      int n = (wn << 6) + (j << 4) + l15;
      const char* nr = bb + n * 128;
#pragma unroll
      for (int ks = 0; ks < 2; ++ks)
        bfr[j][ks] = *(const bf16x8*)(nr + ((((ks << 2) | g) ^ (n & 7)) << 4));
    }
    RDAF(0, 0);
    RDAF(1, 1);          // next phase's fragments, issued ahead of MFMA
    MM(0, 0);

    // ---- phases 1..3: stage ring; read af(p+1) under MFMA(p) ----
#pragma unroll
    for (int p = 1; p < 4; ++p) {
      __builtin_amdgcn_s_barrier();
      if (st2) {
        if (p == 1)      { stageB(t + 2, 0); stageB(t + 2, 1); }
        else if (p == 2) { stageB(t + 2, 2); stageB(t + 2, 3); stageA(t + 2, 0); }
        else             { stageA(t + 2, 2); }
      }
      if (p < 3) RDAF(p + 1, (p + 1) & 1);
      MM(p, p & 1);
    }
    __builtin_amdgcn_s_barrier();   // tile-end: A l=1,3 regions die here
  };

  // prologue: stage tiles 0,1 fully (16 loads/thread)
#pragma unroll
  for (int l = 0; l < 4; ++l) stageA(0, l);
#pragma unroll
  for (int l = 0; l < 4; ++l) stageB(0, l);
#pragma unroll
  for (int l = 0; l < 4; ++l) stageA(1, l);
#pragma unroll
  for (int l = 0; l < 4; ++l) stageB(1, l);

  // t = 0 (tile 1's A-tail already staged by prologue)
  asm volatile("s_waitcnt vmcnt(8)" ::: "memory");
  __builtin_amdgcn_s_barrier();
  TILE(0, false, true);

  // steady state: t = 1..125
  for (int t = 1; t < 126; ++t) {
    asm volatile("s_waitcnt vmcnt(6)" ::: "memory");
    __builtin_amdgcn_s_barrier();
    TILE(t, true, true);
  }

  // t = 126 (stage A-tail of 127; no t+2)
  asm volatile("s_waitcnt vmcnt(6)" ::: "memory");
  __builtin_amdgcn_s_barrier();
  TILE(126, true, false);

  // t = 127 (drain)
  asm volatile("s_waitcnt vmcnt(0)" ::: "memory");
  __builtin_amdgcn_s_barrier();
  TILE(127, false, false);

  // epilogue: C fp32 stores
#pragma unroll
  for (int i = 0; i < 8; ++i) {
#pragma unroll
    for (int rr = 0; rr < 4; ++rr) {
      float* cp = C + (long)(m0 + (wm << 7) + (i << 4) + ((lane >> 4) << 2) + rr) * DIM
                    + n0 + (wn << 6) + l15;
#pragma unroll
      for (int j = 0; j < 4; ++j)
        cp[j * 16] = acc[i][j][rr];
    }
  }
}

// ------------------------------- launcher ----------------------------------
extern "C" void kernel_launch(void* const* d_in, const int* in_sizes, int n_in,
                              void* d_out, int out_size, void* d_ws, size_t ws_size,
                              hipStream_t stream) {
  const float* xq     = (const float*)d_in[0];
  const float* keys   = (const float*)d_in[1];
  const float* values = (const float*)d_in[2];
  const float* mask   = (const float*)d_in[3];
  const float* wo     = (const float*)d_in[4];
  float* out = (float*)d_out;
  char* ws = (char*)d_ws;

  bf16* woB = (bf16*)ws;                                   // 128 MB
  bf16* qB  = (bf16*)(ws + 134217728ull);                  //  32 MB
  bf16* kB  = (bf16*)(ws + 134217728ull + 33554432ull);    //   4 MB
  bf16* vT  = (bf16*)(ws + 134217728ull + 37748736ull);    //   4 MB
  bf16* aB  = (bf16*)(ws + 134217728ull + 41943040ull);    //  32 MB

  cvt_all<<<dim3(2560), dim3(256), 0, stream>>>(wo, xq, keys, woB, qB, kB);
  cvt_vT_kernel<<<dim3(256), dim3(256), 0, stream>>>(values, vT);
  attn_kernel<<<dim3(1024),  dim3(256), 0, stream>>>(qB, kB, vT, mask, aB);
  gemm_bt<<<dim3(256),       dim3(512), 0, stream>>>(aB, woB, out);
}

// Round 22
// 500.807 us; speedup vs baseline: 1.1108x; 1.0115x over previous
//
#include <hip/hip_runtime.h>
#include <hip/hip_bf16.h>
#include <stdint.h>

// ---------------------------------------------------------------------------
// PytorchLlamaSDPA: GQA attention (64 q-heads, 8 kv-heads, S=KV=2048, D=128)
// + additive mask (s,t) + softmax + PV + output projection (8192x8192^T).
// bf16 MFMA, fp32 softmax/accum.
// Attention: r16 structure + log2-domain softmax with bare v_exp_f32
//   (Q pre-scaled by scale*log2e; mask folded via fmaf; raw asm exp2).
// GEMM: r21 (best): 4-phase ring-staged schedule + register-dbuf A frags.
// Converts: merged flat fp32->bf16 kernel + V^T transpose kernel.
// ---------------------------------------------------------------------------

typedef __bf16 bf16;
typedef __attribute__((ext_vector_type(8))) __bf16 bf16x8;
typedef __attribute__((ext_vector_type(4))) __bf16 bf16x4;
typedef __attribute__((ext_vector_type(4))) float f32x4;
typedef __attribute__((ext_vector_type(16))) float f32x16;
typedef __attribute__((ext_vector_type(4))) unsigned int u32x4;

#define N_HEADS 64
#define N_KVH   8
#define HDIM    128
#define SEQ     2048
#define KVL     2048
#define DIM     8192
#define LOG2E   1.4426950408889634f

__device__ __forceinline__ void gload16(const void* g, void* l) {
  __builtin_amdgcn_global_load_lds((const __attribute__((address_space(1))) void*)g,
                                   (__attribute__((address_space(3))) void*)l,
                                   16, 0, 0);
}

// bare hardware exp2 (v_exp_f32 computes 2^x); avoids libm guard of exp2f
__device__ __forceinline__ float exp2_raw(float x) {
  float r;
  asm("v_exp_f32 %0, %1" : "=v"(r) : "v"(x));
  return r;
}

// pack two floats to one u32 of two bf16 (lo in bits 15:0) - pure bit ops
__device__ __forceinline__ unsigned pack2(float lo, float hi) {
  union { bf16 h; unsigned short u; } a, b;
  a.h = (bf16)lo; b.h = (bf16)hi;
  return ((unsigned)b.u << 16) | (unsigned)a.u;
}

// cross-half exchange via v_permlane32_swap_b32 (verified r11)
__device__ __forceinline__ void exch(unsigned a, unsigned b, unsigned& r0, unsigned& r1) {
  asm("v_permlane32_swap_b32 %0, %1" : "+v"(a), "+v"(b));
  r0 = a; r1 = b;
}

// Build two PV B-operand fragments (kv-slices of 16) from one 32-kv P strip.
__device__ __forceinline__ void buildfrags(const float (&p)[16], bf16x8& f0, bf16x8& f1) {
  unsigned pk0 = pack2(p[0],  p[1]),  pk1 = pack2(p[2],  p[3]);
  unsigned pk2 = pack2(p[4],  p[5]),  pk3 = pack2(p[6],  p[7]);
  unsigned pk4 = pack2(p[8],  p[9]),  pk5 = pack2(p[10], p[11]);
  unsigned pk6 = pack2(p[12], p[13]), pk7 = pack2(p[14], p[15]);
  unsigned a0, a1, b0, b1, c0, c1, d0, d1;
  exch(pk0, pk2, a0, a1);
  exch(pk1, pk3, b0, b1);
  exch(pk4, pk6, c0, c1);
  exch(pk5, pk7, d0, d1);
  u32x4 w0 = { a0, b0, a1, b1 };
  u32x4 w1 = { c0, d0, c1, d1 };
  f0 = __builtin_bit_cast(bf16x8, w0);
  f1 = __builtin_bit_cast(bf16x8, w1);
}

// ---------------- merged flat fp32 -> bf16 (wo, xq, keys) ------------------
#define WO_F4  16777216l
#define XQ_F4   4194304l
#define K_F4     524288l
__global__ void cvt_all(const float* __restrict__ wo, const float* __restrict__ xq,
                        const float* __restrict__ ks,
                        bf16* __restrict__ woB, bf16* __restrict__ qB,
                        bf16* __restrict__ kB) {
  long i = (long)blockIdx.x * blockDim.x + threadIdx.x;
  const long stride = (long)gridDim.x * blockDim.x;
  const long total = WO_F4 + XQ_F4 + K_F4;
  for (; i < total; i += stride) {
    const float* src; bf16* dst; float sc; long j;
    if (i < WO_F4)              { src = wo; dst = woB; sc = 1.0f; j = i; }
    else if (i < WO_F4 + XQ_F4) { src = xq; dst = qB;  sc = 0.12751744154f; j = i - WO_F4; }  // (1/sqrt(128))*log2e
    else                        { src = ks; dst = kB;  sc = 1.0f; j = i - WO_F4 - XQ_F4; }
    float4 v = ((const float4*)src)[j];
    bf16x4 o = { (bf16)(v.x * sc), (bf16)(v.y * sc),
                 (bf16)(v.z * sc), (bf16)(v.w * sc) };
    *(bf16x4*)(dst + j * 4) = o;
  }
}

// ------------------- values (kh,t,d) -> bf16 V^T (kh,d,t) ------------------
__global__ void cvt_vT_kernel(const float* __restrict__ v, bf16* __restrict__ vT) {
  __shared__ bf16 tile[64][132];
  const int tid = threadIdx.x;
  const int kh = blockIdx.x >> 5;
  const int t0 = (blockIdx.x & 31) << 6;
  const float* src = v + ((long)kh * KVL + t0) * HDIM;
#pragma unroll
  for (int it = 0; it < 8; ++it) {
    int q = it * 256 + tid;
    int r = q >> 5;
    int c4 = (q & 31) << 2;
    float4 val = *(const float4*)(src + (long)r * HDIM + c4);
    bf16x4 o = { (bf16)val.x, (bf16)val.y, (bf16)val.z, (bf16)val.w };
    *(bf16x4*)&tile[r][c4] = o;
  }
  __syncthreads();
  const int t = tid & 63;
  const int dbase = tid >> 6;
#pragma unroll
  for (int it = 0; it < 32; ++it) {
    int d = it * 4 + dbase;
    vT[((long)kh * HDIM + d) * KVL + t0 + t] = tile[t][d];
  }
}

// ------------------------------- attention ---------------------------------
// r16 structure: Grid 1024 = 64 heads x 16 q-blocks of 128 rows, 256 threads
// (4 warps), 2 blocks/CU. K dbuf 2x16KB [0,32K) + V d-paired dbuf 2x16KB
// [32K,64K). All LDS reads <=2-way banked. Log2-domain softmax:
// Q pre-scaled by scale*log2e, mask folded with fmaf(mk, log2e, s),
// bare v_exp_f32 for all exponentials, THR = 8*log2e.
__global__ __launch_bounds__(256, 2) void attn_kernel(
    const bf16* __restrict__ qB, const bf16* __restrict__ kB,
    const bf16* __restrict__ vT, const float* __restrict__ mask,
    bf16* __restrict__ attnB)
{
  __shared__ __align__(16) char lds[65536];

  const int tid  = threadIdx.x;
  const int lane = tid & 63;
  const int w    = tid >> 6;       // 0..3
  const int ihi  = lane >> 5;
  const int l31  = lane & 31;

  const int bid = blockIdx.x;
  const int h   = bid >> 4;
  const int q0b = (bid & 15) << 7;
  const int kh  = h >> 3;

  // ---- stage Q [128 rows][256B], key &15 ----
#pragma unroll
  for (int rnd = 0; rnd < 8; ++rnd) {
    int row = rnd * 16 + w * 4 + (lane >> 4);
    int cg  = (lane & 15) ^ (row & 15);
    const bf16* g = qB + (((long)(q0b + row) * N_HEADS + h) << 7) + (cg << 3);
    gload16(g, lds + rnd * 4096 + w * 1024);
  }
  __syncthreads();

  bf16x8 qf[8];
  {
    int qrow = (w << 5) + l31;      // 0..127
    const char* qr = lds + qrow * 256;
#pragma unroll
    for (int s = 0; s < 8; ++s)
      qf[s] = *(const bf16x8*)(qr + ((((s << 1) | ihi) ^ (qrow & 15)) << 4));
  }
  __syncthreads();   // Q area freed -> K double buffer

  // ---- stage K/V tile 0 into buffer 0 ----
  {
#pragma unroll
    for (int rnd = 0; rnd < 4; ++rnd) {
      int row = rnd * 16 + w * 4 + (lane >> 4);
      int cg  = (lane & 15) ^ (row & 15);
      const bf16* g = kB + (((long)(kh * KVL + row)) << 7) + (cg << 3);
      gload16(g, lds + rnd * 4096 + w * 1024);
    }
#pragma unroll
    for (int rnd = 0; rnd < 4; ++rnd) {
      int vr = rnd * 16 + w * 4 + (lane >> 4);     // pair-row 0..63
      int gg = (lane & 15) ^ (vr & 15);
      int dsrc = (vr << 1) | (gg >> 3);
      const bf16* gp = vT + ((long)(kh * HDIM + dsrc) * KVL) + ((gg & 7) << 3);
      gload16(gp, lds + 32768 + rnd * 4096 + w * 1024);
    }
  }
  __syncthreads();

  const float* mrow = mask + (size_t)(q0b + (w << 5) + l31) * KVL + (ihi << 2);

  f32x16 acc[4];
#pragma unroll
  for (int dt = 0; dt < 4; ++dt) acc[dt] = {};
  float m_run = -1e30f, l_run = 0.f;

  for (int kt = 0; kt < KVL / 64; ++kt) {
    const int cur = kt & 1;
    const int kv0 = kt << 6;

    if (kt < KVL / 64 - 1) {
      const int kv0n = kv0 + 64;
#pragma unroll
      for (int rnd = 0; rnd < 4; ++rnd) {
        int row = rnd * 16 + w * 4 + (lane >> 4);
        int cg  = (lane & 15) ^ (row & 15);
        const bf16* g = kB + (((long)(kh * KVL + kv0n + row)) << 7) + (cg << 3);
        gload16(g, lds + (cur ^ 1) * 16384 + rnd * 4096 + w * 1024);
      }
#pragma unroll
      for (int rnd = 0; rnd < 4; ++rnd) {
        int vr = rnd * 16 + w * 4 + (lane >> 4);
        int gg = (lane & 15) ^ (vr & 15);
        int dsrc = (vr << 1) | (gg >> 3);
        const bf16* gp = vT + ((long)(kh * HDIM + dsrc) * KVL) + kv0n + ((gg & 7) << 3);
        gload16(gp, lds + 32768 + (cur ^ 1) * 16384 + rnd * 4096 + w * 1024);
      }
    }

    const float* mrt = mrow + kv0;
    f32x4 mk0[4], mk1[4];
#pragma unroll
    for (int rq = 0; rq < 4; ++rq) {
      mk0[rq] = *(const f32x4*)(mrt + (rq << 3));
      mk1[rq] = *(const f32x4*)(mrt + 32 + (rq << 3));
    }

    const char* kb = lds + cur * 16384;
    f32x16 s0 = {}, s1 = {};
    const int kr0 = l31, kr1 = 32 + l31;
    __builtin_amdgcn_s_setprio(1);
#pragma unroll
    for (int s = 0; s < 8; ++s) {
      bf16x8 kf0 = *(const bf16x8*)(kb + kr0 * 256 + ((((s << 1) | ihi) ^ (kr0 & 15)) << 4));
      s0 = __builtin_amdgcn_mfma_f32_32x32x16_bf16(kf0, qf[s], s0, 0, 0, 0);
      bf16x8 kf1 = *(const bf16x8*)(kb + kr1 * 256 + ((((s << 1) | ihi) ^ (kr1 & 15)) << 4));
      s1 = __builtin_amdgcn_mfma_f32_32x32x16_bf16(kf1, qf[s], s1, 0, 0, 0);
    }
    __builtin_amdgcn_s_setprio(0);

    // p = S (already log2-scaled via Q) + mask*log2e  (fmaf = cost of the add)
    float p0[16], p1[16];
#pragma unroll
    for (int rq = 0; rq < 4; ++rq) {
#pragma unroll
      for (int j = 0; j < 4; ++j) {
        p0[rq * 4 + j] = fmaf(mk0[rq][j], LOG2E, s0[rq * 4 + j]);
        p1[rq * 4 + j] = fmaf(mk1[rq][j], LOG2E, s1[rq * 4 + j]);
      }
    }

    // ---- online softmax, log2 domain, defer-max (THR = 8*log2e) ----
    float q00 = fmaxf(fmaxf(p0[0],  p0[1]),  fmaxf(p0[2],  p0[3]));
    float q01 = fmaxf(fmaxf(p0[4],  p0[5]),  fmaxf(p0[6],  p0[7]));
    float q02 = fmaxf(fmaxf(p0[8],  p0[9]),  fmaxf(p0[10], p0[11]));
    float q03 = fmaxf(fmaxf(p0[12], p0[13]), fmaxf(p0[14], p0[15]));
    float q10 = fmaxf(fmaxf(p1[0],  p1[1]),  fmaxf(p1[2],  p1[3]));
    float q11 = fmaxf(fmaxf(p1[4],  p1[5]),  fmaxf(p1[6],  p1[7]));
    float q12 = fmaxf(fmaxf(p1[8],  p1[9]),  fmaxf(p1[10], p1[11]));
    float q13 = fmaxf(fmaxf(p1[12], p1[13]), fmaxf(p1[14], p1[15]));
    float mx = fmaxf(fmaxf(fmaxf(q00, q01), fmaxf(q02, q03)),
                     fmaxf(fmaxf(q10, q11), fmaxf(q12, q13)));
    mx = fmaxf(mx, __shfl_xor(mx, 32));
    if (!__all((int)(mx - m_run <= 11.5415603f))) {
      float nm = fmaxf(m_run, mx);
      float al = exp2_raw(m_run - nm);
      m_run = nm;
      l_run *= al;
#pragma unroll
      for (int dt = 0; dt < 4; ++dt) acc[dt] *= al;
    }
    float ps = 0.f;
#pragma unroll
    for (int i = 0; i < 16; ++i) { p0[i] = exp2_raw(p0[i] - m_run); ps += p0[i]; }
#pragma unroll
    for (int i = 0; i < 16; ++i) { p1[i] = exp2_raw(p1[i] - m_run); ps += p1[i]; }
    ps += __shfl_xor(ps, 32);
    l_run += ps;

    bf16x8 pfrag[4];
    buildfrags(p0, pfrag[0], pfrag[1]);
    buildfrags(p1, pfrag[2], pfrag[3]);

    // ---- PV: O^T[d][q] += V^T[d][kv] * P[kv][q]; V from d-paired LDS ----
    const char* vb = lds + 32768 + cur * 16384;
    const int par8 = (l31 & 1) << 3;
    __builtin_amdgcn_s_setprio(1);
#pragma unroll
    for (int dt = 0; dt < 4; ++dt) {
      const int vrow = (dt << 4) + (l31 >> 1);
      const char* vrp = vb + vrow * 256;
#pragma unroll
      for (int ks = 0; ks < 4; ++ks) {
        int c16 = par8 | (ks << 1) | ihi;
        bf16x8 vf = *(const bf16x8*)(vrp + ((c16 ^ (vrow & 15)) << 4));
        acc[dt] = __builtin_amdgcn_mfma_f32_32x32x16_bf16(vf, pfrag[ks], acc[dt], 0, 0, 0);
      }
    }
    __builtin_amdgcn_s_setprio(0);
    __syncthreads();
  }

  // ---- epilogue: normalize, LDS transpose (key &15), coalesced stores ----
  const float linv = 1.0f / l_run;
  char* ep = lds + (w << 13);      // per-warp 8KB in [0,32K)
#pragma unroll
  for (int dt = 0; dt < 4; ++dt) {
#pragma unroll
    for (int r = 0; r < 16; ++r) {
      int d = (dt << 5) + (r & 3) + ((r >> 2) << 3) + (ihi << 2);
      int byte = l31 * 256 + (((d >> 3) ^ (l31 & 15)) << 4) + ((d & 7) << 1);
      *(bf16*)(ep + byte) = (bf16)(acc[dt][r] * linv);
    }
  }
  __syncthreads();
  const size_t obase = (size_t)(q0b + (w << 5)) * DIM + h * HDIM;
#pragma unroll
  for (int i = 0; i < 8; ++i) {
    int row = (i << 2) + (lane >> 4);
    int cp  = lane & 15;
    int c   = cp ^ (row & 15);
    bf16x8 ov = *(const bf16x8*)(ep + row * 256 + (cp << 4));
    *(bf16x8*)(attnB + obase + (size_t)row * DIM + (c << 3)) = ov;
  }
}

// ------------------------------ projection GEMM ----------------------------
// r21 (best): 4-phase ring-staged schedule + register-double-buffered A
// fragments (af(p+1) read under phase p's MFMA cluster).
//   B dies after phase 0 -> stage B(t+2) in phases 1,2.
//   A quarters l=0,2 die after phase 1 -> stage in phases 2,3.
//   A l=1,3 die at tile end -> staged at next tile's phase 0.
// Steady-state wait: vmcnt(6).
__global__ __launch_bounds__(512, 2) void gemm_bt(
    const bf16* __restrict__ A, const bf16* __restrict__ B, float* __restrict__ C)
{
  __shared__ __align__(16) char lds[131072];
  const int tid  = threadIdx.x;
  const int lane = tid & 63;
  const int w    = tid >> 6;
  const int wm   = w >> 2;       // 0..1
  const int wn   = w & 3;        // 0..3

  const int bid = blockIdx.x;
  const int m0  = (bid >> 5) << 8;                              // 8 m-panels
  const int n0  = (((bid & 7) << 2) | ((bid >> 3) & 3)) << 8;   // 32 n-panels, XCD-grouped

  const int srow = tid >> 3;                 // 0..63
  const int sch  = (tid & 7) ^ (srow & 7);   // pre-swizzled source chunk
  const bf16* gA0 = A + (long)(m0 + srow) * DIM + (sch << 3);
  const bf16* gB0 = B + (long)(n0 + srow) * DIM + (sch << 3);
  const long rstep = (long)64 * DIM;

  f32x4 acc[8][4];
#pragma unroll
  for (int i = 0; i < 8; ++i)
#pragma unroll
    for (int j = 0; j < 4; ++j) acc[i][j] = { 0.f, 0.f, 0.f, 0.f };

  auto stageA = [&](int kt, int l) {
    const long ko = (long)kt << 6;
    char* s = lds + (kt & 1) * 65536 + tid * 16;
    gload16(gA0 + l * rstep + ko, s + l * 8192);
  };
  auto stageB = [&](int kt, int l) {
    const long ko = (long)kt << 6;
    char* s = lds + (kt & 1) * 65536 + 32768 + tid * 16;
    gload16(gB0 + l * rstep + ko, s + l * 8192);
  };

  const int g = lane >> 4;
  const int l15 = lane & 15;

  auto TILE = [&](int t, bool tailA, bool st2) {
    const char* ab = lds + (t & 1) * 65536;
    const char* bb = ab + 32768;

    bf16x8 bfr[4][2];
    bf16x8 af[2][2][2];   // [slot][e][ks], slot = phase & 1

    auto RDAF = [&](int p, int s) {
#pragma unroll
      for (int e = 0; e < 2; ++e) {
        int m = (wm << 7) + (((p << 1) | e) << 4) + l15;
        const char* mr = ab + m * 128;
#pragma unroll
        for (int ks = 0; ks < 2; ++ks)
          af[s][e][ks] = *(const bf16x8*)(mr + ((((ks << 2) | g) ^ (m & 7)) << 4));
      }
    };
    auto MM = [&](int p, int s) {
      __builtin_amdgcn_s_setprio(1);
#pragma unroll
      for (int e = 0; e < 2; ++e)
#pragma unroll
        for (int j = 0; j < 4; ++j)
#pragma unroll
          for (int ks = 0; ks < 2; ++ks)
            acc[(p << 1) | e][j] = __builtin_amdgcn_mfma_f32_16x16x32_bf16(
                af[s][e][ks], bfr[j][ks], acc[(p << 1) | e][j], 0, 0, 0);
      __builtin_amdgcn_s_setprio(0);
    };

    // ---- phase 0: stage A(t+1) tail; read B, af(0), af(1); MFMA(0) ----
    if (tailA) { stageA(t + 1, 1); stageA(t + 1, 3); }
#pragma unroll
    for (int j = 0; j < 4; ++j) {
      int n = (wn << 6) + (j << 4) + l15;
      const char* nr = bb + n * 128;
#pragma unroll
      for (int ks = 0; ks < 2; ++ks)
        bfr[j][ks] = *(const bf16x8*)(nr + ((((ks << 2) | g) ^ (n & 7)) << 4));
    }
    RDAF(0, 0);
    RDAF(1, 1);
    MM(0, 0);

    // ---- phases 1..3: stage ring; read af(p+1) under MFMA(p) ----
#pragma unroll
    for (int p = 1; p < 4; ++p) {
      __builtin_amdgcn_s_barrier();
      if (st2) {
        if (p == 1)      { stageB(t + 2, 0); stageB(t + 2, 1); }
        else if (p == 2) { stageB(t + 2, 2); stageB(t + 2, 3); stageA(t + 2, 0); }
        else             { stageA(t + 2, 2); }
      }
      if (p < 3) RDAF(p + 1, (p + 1) & 1);
      MM(p, p & 1);
    }
    __builtin_amdgcn_s_barrier();   // tile-end: A l=1,3 regions die here
  };

  // prologue: stage tiles 0,1 fully (16 loads/thread)
#pragma unroll
  for (int l = 0; l < 4; ++l) stageA(0, l);
#pragma unroll
  for (int l = 0; l < 4; ++l) stageB(0, l);
#pragma unroll
  for (int l = 0; l < 4; ++l) stageA(1, l);
#pragma unroll
  for (int l = 0; l < 4; ++l) stageB(1, l);

  asm volatile("s_waitcnt vmcnt(8)" ::: "memory");
  __builtin_amdgcn_s_barrier();
  TILE(0, false, true);

  for (int t = 1; t < 126; ++t) {
    asm volatile("s_waitcnt vmcnt(6)" ::: "memory");
    __builtin_amdgcn_s_barrier();
    TILE(t, true, true);
  }

  asm volatile("s_waitcnt vmcnt(6)" ::: "memory");
  __builtin_amdgcn_s_barrier();
  TILE(126, true, false);

  asm volatile("s_waitcnt vmcnt(0)" ::: "memory");
  __builtin_amdgcn_s_barrier();
  TILE(127, false, false);

  // epilogue: C fp32 stores
#pragma unroll
  for (int i = 0; i < 8; ++i) {
#pragma unroll
    for (int rr = 0; rr < 4; ++rr) {
      float* cp = C + (long)(m0 + (wm << 7) + (i << 4) + ((lane >> 4) << 2) + rr) * DIM
                    + n0 + (wn << 6) + l15;
#pragma unroll
      for (int j = 0; j < 4; ++j)
        cp[j * 16] = acc[i][j][rr];
    }
  }
}

// ------------------------------- launcher ----------------------------------
extern "C" void kernel_launch(void* const* d_in, const int* in_sizes, int n_in,
                              void* d_out, int out_size, void* d_ws, size_t ws_size,
                              hipStream_t stream) {
  const float* xq     = (const float*)d_in[0];
  const float* keys   = (const float*)d_in[1];
  const float* values = (const float*)d_in[2];
  const float* mask   = (const float*)d_in[3];
  const float* wo     = (const float*)d_in[4];
  float* out = (float*)d_out;
  char* ws = (char*)d_ws;

  bf16* woB = (bf16*)ws;                                   // 128 MB
  bf16* qB  = (bf16*)(ws + 134217728ull);                  //  32 MB
  bf16* kB  = (bf16*)(ws + 134217728ull + 33554432ull);    //   4 MB
  bf16* vT  = (bf16*)(ws + 134217728ull + 37748736ull);    //   4 MB
  bf16* aB  = (bf16*)(ws + 134217728ull + 41943040ull);    //  32 MB

  cvt_all<<<dim3(2560), dim3(256), 0, stream>>>(wo, xq, keys, woB, qB, kB);
  cvt_vT_kernel<<<dim3(256), dim3(256), 0, stream>>>(values, vT);
  attn_kernel<<<dim3(1024),  dim3(256), 0, stream>>>(qB, kB, vT, mask, aB);
  gemm_bt<<<dim3(256),       dim3(512), 0, stream>>>(aB, woB, out);
}